// Round 15
// baseline (716.449 us; speedup 1.0000x reference)
//
#include <hip/hip_runtime.h>
#include <math.h>
#include <type_traits>

typedef __attribute__((ext_vector_type(8))) short s8v;   // 8 bf16 (4 VGPR)
typedef __attribute__((ext_vector_type(4))) float f4v;   // MFMA acc
typedef __attribute__((ext_vector_type(2))) float f2v;   // packed f32 pair

#define CH 8192

// ---------------- bf16 bit helpers ----------------
__device__ inline float b2f(unsigned short u){ return __uint_as_float(((unsigned)u)<<16); }
__device__ inline unsigned short f2b(float f){
  unsigned u = __float_as_uint(f);
  return (unsigned short)((u + 0x7FFFu + ((u>>16)&1u)) >> 16);   // RNE
}
__device__ inline void stC(float* p, float v){ *p = v; }
__device__ inline void stC(unsigned short* p, float v){ *p = f2b(v); }

// async global->LDS, 16B per lane; lds base must be wave-uniform
__device__ __forceinline__ void gl16(const void* g, void* l){
  __builtin_amdgcn_global_load_lds(
      (const __attribute__((address_space(1))) unsigned*)g,
      (__attribute__((address_space(3))) unsigned*)l, 16, 0, 0);
}

// ================= compile-time real Wigner (CG) tables =================
constexpr double FCT[11] = {1.,1.,2.,6.,24.,120.,720.,5040.,40320.,362880.,3628800.};
constexpr double csqrt_c(double x){
  double g = x > 1.0 ? x : 1.0;
  for (int i=0;i<60;i++) g = 0.5*(g + x/g);
  return g;
}
struct CD { double re, im; };
constexpr CD cmulc(CD a, CD b){ return {a.re*b.re - a.im*b.im, a.re*b.im + a.im*b.re}; }

constexpr double su2cg_c(int j1,int j2,int j3,int m1,int m2,int m3){
  if (m1+m2 != m3) return 0.0;
  double pref = csqrt_c((double)(2*j3+1) * FCT[j1+j2-j3]*FCT[j1-j2+j3]*FCT[-j1+j2+j3]/FCT[j1+j2+j3+1]
              * FCT[j3+m3]*FCT[j3-m3]*FCT[j1-m1]*FCT[j1+m1]*FCT[j2-m2]*FCT[j2+m2]);
  int kmin = 0;
  if (j2-j3-m1 > kmin) kmin = j2-j3-m1;
  if (j1-j3+m2 > kmin) kmin = j1-j3+m2;
  int kmax = j1+j2-j3;
  if (j1-m1 < kmax) kmax = j1-m1;
  if (j2+m2 < kmax) kmax = j2+m2;
  double s = 0.0;
  for (int k=kmin;k<=kmax;k++){
    double t = 1.0/(FCT[k]*FCT[j1+j2-j3-k]*FCT[j1-m1-k]*FCT[j2+m2-k]*FCT[j3-j2+m1+k]*FCT[j3-j1-m2+k]);
    s += (k&1) ? -t : t;
  }
  return pref*s;
}

constexpr CD qelem_c(int l, int i, int j){
  int m = i - l;
  const double is2 = 0.70710678118654752440;
  double re=0.0, im=0.0;
  if (m < 0){
    if (j == l - m) re = is2;
    else if (j == l + m) im = -is2;
  } else if (m == 0){
    if (j == l) re = 1.0;
  } else {
    double sgn = (m & 1) ? -1.0 : 1.0;
    if (j == l + m) re = sgn*is2;
    else if (j == l - m) im = sgn*is2;
  }
  CD r{};
  switch (l & 3){                    // (-i)^l
    case 0: r = {re, im}; break;
    case 1: r = {im, -re}; break;
    case 2: r = {-re, -im}; break;
    default: r = {-im, re}; break;
  }
  return r;
}

// path-count normalization per l3: n = {4,9,11,10}
constexpr double TN3[4] = {0.5, 1.0/3.0, 0.30151134457776363, 0.31622776601683794};

template<int L1,int L2,int L3>
struct TriVals { float v[(2*L1+1)*(2*L2+1)*(2*L3+1)]; };

template<int L1,int L2,int L3>
constexpr TriVals<L1,L2,L3> make_tri(){
  constexpr int n1=2*L1+1, n2=2*L2+1, n3=2*L3+1;
  double cg[n1*n2*n3] = {};
  for (int a=0;a<n1;a++)
    for (int b=0;b<n2;b++)
      for (int c=0;c<n3;c++)
        cg[(a*n2+b)*n3+c] = su2cg_c(L1,L2,L3, a-L1, b-L2, c-L3);
  double cr[n1*n2*n3] = {};
  double ci[n1*n2*n3] = {};
  for (int i=0;i<n1;i++)
   for (int j=0;j<n2;j++)
    for (int k=0;k<n3;k++){
      double sre=0.0, sim=0.0;
      for (int a=0;a<n1;a++){
        CD q1 = qelem_c(L1,i,a);
        if (q1.re==0.0 && q1.im==0.0) continue;
        for (int b=0;b<n2;b++){
          CD q2 = qelem_c(L2,j,b);
          if (q2.re==0.0 && q2.im==0.0) continue;
          CD q12 = cmulc(q1,q2);
          for (int c=0;c<n3;c++){
            double g = cg[(a*n2+b)*n3+c];
            if (g == 0.0) continue;
            CD q3 = qelem_c(L3,k,c);
            CD q3c{q3.re, -q3.im};
            CD q = cmulc(q12,q3c);
            sre += q.re*g; sim += q.im*g;
          }
        }
      }
      cr[(i*n2+j)*n3+k]=sre; ci[(i*n2+j)*n3+k]=sim;
    }
  double nr=0.0, ni=0.0;
  for (int i=0;i<n1*n2*n3;i++){ nr += cr[i]*cr[i]; ni += ci[i]*ci[i]; }
  bool pr = nr >= ni;
  double nn = csqrt_c(pr ? nr : ni);
  TriVals<L1,L2,L3> t{};
  for (int i=0;i<n1*n2*n3;i++)
    t.v[i] = (float)(((pr ? cr[i] : ci[i]) / nn) * TN3[L3]);
  return t;
}

template<int L1,int L2,int L3>
constexpr TriVals<L1,L2,L3> W3V = make_tri<L1,L2,L3>();

constexpr int LOFFC[4] = {0,1,4,9};

// ---- FMA with inline 32-bit literal (VOP2 v_fmac_f32, src0=literal: free) ----
template<int WB>
__device__ __forceinline__ void fmac_lit(float& a, float p){
  asm("v_fmac_f32 %0, %2, %1" : "+v"(a) : "v"(p), "i"(WB));
}

// static-for
template<int I, int N, typename F>
__device__ __forceinline__ void sfor(F&& f){
  if constexpr (I < N){
    f(std::integral_constant<int,I>{});
    sfor<I+1,N>(static_cast<F&&>(f));
  }
}

// grouped TP: one (L1,L2) pair -> each product computed ONCE, all valid l3 emitted
template<int L1,int L2>
__device__ __forceinline__ void tp_pair(const float* __restrict__ env,
                                        const float* __restrict__ v,
                                        float* __restrict__ acc){
  sfor<0,2*L1+1>([&](auto K1c){
    constexpr int k1 = decltype(K1c)::value;
    sfor<0,2*L2+1>([&](auto K2c){
      constexpr int k2 = decltype(K2c)::value;
      float p = env[LOFFC[L1]+k1] * v[LOFFC[L2]+k2];
      sfor<0,4>([&](auto L3c){
        constexpr int l3 = decltype(L3c)::value;
        constexpr int lo = (L1>L2)?(L1-L2):(L2-L1);
        if constexpr (l3 >= lo && l3 <= L1+L2){
          sfor<0,2*l3+1>([&](auto K3c){
            constexpr int k3 = decltype(K3c)::value;
            constexpr float w = W3V<L1,L2,l3>.v[(k1*(2*L2+1)+k2)*(2*l3+1)+k3];
            if constexpr (w != 0.f){
              fmac_lit<__builtin_bit_cast(int, w)>(acc[LOFFC[l3]+k3], p);
            }
          });
        }
      });
    });
  });
}

// scalar per-triple variant (tp_last, l3=0 only: tiny)
template<int L1,int L2,int L3>
__device__ __forceinline__ void tp_tri(const float* __restrict__ env,
                                       const float* __restrict__ v,
                                       float* __restrict__ acc){
  constexpr int n1=2*L1+1, n2=2*L2+1, n3=2*L3+1;
  #pragma unroll
  for (int k1=0;k1<n1;k1++)
    #pragma unroll
    for (int k2=0;k2<n2;k2++){
      float p = env[LOFFC[L1]+k1] * v[LOFFC[L2]+k2];
      #pragma unroll
      for (int k3=0;k3<n3;k3++){
        float w = W3V<L1,L2,L3>.v[(k1*n2+k2)*n3+k3];
        if (w != 0.f) acc[LOFFC[L3]+k3] += w * p;
      }
    }
}

// ---------------- batched weight convert (+optional transpose) ----------------
struct WSeg { const float* W; unsigned short* WT; int K, N, Kpad, nblk, trans; };
struct WDesc { WSeg s[10]; };
__global__ __launch_bounds__(256) void wconv_all(WDesc d){
  int b = blockIdx.x;
  int seg = 0;
  while (b >= d.s[seg].nblk){ b -= d.s[seg].nblk; ++seg; }
  const WSeg w = d.s[seg];
  int idx = b*256 + threadIdx.x;
  if (w.trans){
    if (idx >= w.N*w.Kpad) return;
    int n = idx / w.Kpad, k = idx - n*w.Kpad;
    w.WT[idx] = (k < w.K) ? f2b(w.W[(size_t)k*w.N + n]) : (unsigned short)0;
  } else {
    if (idx >= w.K*w.N) return;
    w.WT[idx] = f2b(w.W[idx]);
  }
}

// ---------------- fused output vector: fv = wlat1_l1 @ wout (fp32) -------------
__global__ __launch_bounds__(256) void wfuse_vec(
    const float* __restrict__ wl1_l1, const float* __restrict__ wout,
    float* __restrict__ fv)
{
  int k = blockIdx.x*256 + threadIdx.x;
  if (k >= 512) return;
  float s = 0.f;
  for (int n=0;n<512;n++) s += wl1_l1[(size_t)k*512 + n] * wout[n];
  fv[k] = s;
}

// ---------------- edge geometry + receiver histogram ----------------
__global__ __launch_bounds__(256) void edge_init(
    const float* __restrict__ vec, const float* __restrict__ na,
    const int* __restrict__ snd, const int* __restrict__ rcv,
    unsigned short* __restrict__ feat, float* __restrict__ Y, float* __restrict__ cutb,
    int* __restrict__ deg, int E)
{
  int e = blockIdx.x*256 + threadIdx.x;
  if (e >= E) return;
  float vx = vec[(size_t)e*3], vy = vec[(size_t)e*3+1], vz = vec[(size_t)e*3+2];
  float d = sqrtf(vx*vx + vy*vy + vz*vz);
  float inv = 1.f/(d + 1e-9f);
  float x = vx*inv, y = vy*inv, z = vz*inv;
  float dc = d * 0.4f;               // d / 2.5
  float dci = 1.f/(dc + 1e-9f);
  unsigned short* f = feat + (size_t)e*64;
  #pragma unroll
  for (int k=1;k<=8;k++)
    f[k-1] = f2b(1.41421356237309515f * sinf(dc * 3.14159265358979323846f * k) * dci);
  int s = snd[e], r = rcv[e];
  atomicAdd(&deg[r], 1);             // CSR histogram (fused; deg pre-zeroed)
  #pragma unroll
  for (int i=0;i<16;i++) f[8+i]  = f2b(na[(size_t)s*16+i]);
  #pragma unroll
  for (int i=0;i<16;i++) f[24+i] = f2b(na[(size_t)r*16+i]);
  #pragma unroll
  for (int i=40;i<64;i++) f[i] = 0;
  float cv = 0.f;
  if (dc < 1.f){
    float d2 = dc*dc; float d6 = d2*d2*d2; float d7 = d6*dc; float d8 = d7*dc;
    cv = 1.f - 28.f*d6 + 48.f*d7 - 21.f*d8;
  }
  cutb[e] = cv;
  float* Ye = Y + (size_t)e*16;
  const float s3=1.7320508075688772f, s5=2.2360679774997896f, s15=3.8729833462074170f;
  Ye[0] = 1.f;
  Ye[1] = s3*y; Ye[2] = s3*z; Ye[3] = s3*x;
  Ye[4] = s15*x*y; Ye[5] = s15*y*z; Ye[6] = 0.5f*s5*(3.f*z*z-1.f);
  Ye[7] = s15*x*z; Ye[8] = 0.5f*s15*(x*x - y*y);
  const float c1=2.0916500663351889f, c2=10.246950765959598f, c3=1.6201851746019649f, c4=1.3228756555322954f;
  Ye[9]  = c1*y*(3.f*x*x - y*y);
  Ye[10] = c2*x*y*z;
  Ye[11] = c3*y*(5.f*z*z - 1.f);
  Ye[12] = c4*z*(5.f*z*z - 3.f);
  Ye[13] = c3*x*(5.f*z*z - 1.f);
  Ye[14] = 0.5f*c2*z*(x*x - y*y);
  Ye[15] = c1*x*(x*x - 3.f*y*y);
}

// ---------------- MFMA bf16 GEMM with global_load_lds staging ------------------
// TSTORE: write C transposed (C[col*ldc+row]) — used for weight-fusion GEMMs.
template<int NT, typename TC, bool SILU, bool CUT, bool TSTORE=false>
__global__ __launch_bounds__(256) void gemm_mfma(
    const unsigned short* __restrict__ A, int lda, int K1,
    const unsigned short* __restrict__ WT, int ldw,
    TC* __restrict__ C, int ldc,
    const float* __restrict__ cutv,
    int N, int K, float scale)
{
  constexpr int NB = NT/16;
  __shared__ s8v As8[128*8];
  __shared__ s8v Bs8[NT*8];
  const int tid = threadIdx.x;
  const int wid = tid >> 6, lane = tid & 63;
  const int r15 = lane & 15, kg = lane >> 4;
  const int col0 = blockIdx.x * NT;
  const int row0 = blockIdx.y * 128;
  f4v acc[2][NB] = {};

  auto compute = [&](){
    #pragma unroll
    for (int s = 0; s < 2; s++) {
      const int cb = s*4 + kg;
      const int cx = cb ^ (r15 & 7);
      s8v a0 = As8[(wid*32      + r15)*8 + cx];
      s8v a1 = As8[(wid*32 + 16 + r15)*8 + cx];
      #pragma unroll
      for (int j = 0; j < NB; j++) {
        s8v b = Bs8[(j*16 + r15)*8 + cx];
        acc[0][j] = __builtin_amdgcn_mfma_f32_16x16x32_bf16(a0, b, acc[0][j], 0,0,0);
        acc[1][j] = __builtin_amdgcn_mfma_f32_16x16x32_bf16(a1, b, acc[1][j], 0,0,0);
      }
    }
  };

  for (int k0 = 0; k0 < K; k0 += 64) {
    #pragma unroll
    for (int i = 0; i < 4; i++) {       // A tile: 1024 segs of 16B
      int seg = i*256 + tid;
      int r = seg >> 3, ks = seg & 7;
      int ksx = ks ^ (r & 7);
      gl16(A + (size_t)(row0+r)*lda + k0 + ksx*8, &As8[i*256 + (tid & ~63)]);
    }
    #pragma unroll
    for (int i = 0; i < NT/32; i++) {   // B tile: NT*8 segs
      int seg = i*256 + tid;
      int n = seg >> 3, ks = seg & 7;
      int ksx = ks ^ (n & 7);
      gl16(WT + (size_t)(col0+n)*ldw + k0 + ksx*8, &Bs8[i*256 + (tid & ~63)]);
    }
    __syncthreads();
    compute();
    __syncthreads();
  }
  // epilogue: C/D layout col = lane&15, row = (lane>>4)*4 + j
  #pragma unroll
  for (int g=0; g<2; g++) {
    #pragma unroll
    for (int c=0; c<NB; c++) {
      int col = col0 + c*16 + r15;
      if (col >= N) continue;
      #pragma unroll
      for (int j=0;j<4;j++) {
        int row = row0 + wid*32 + g*16 + kg*4 + j;
        float v = acc[g][c][j] * scale;
        if (SILU) v = v / (1.f + __expf(-v));
        if (CUT)  v *= cutv[row];
        if (TSTORE) stC(&C[(size_t)col*ldc + row], v);
        else        stC(&C[(size_t)row*ldc + col], v);
      }
    }
  }
}

// ---------------- V init: thread per (e,m); wi = xb cols [544..672) ------------
__global__ __launch_bounds__(256) void vbuild(
    const unsigned short* __restrict__ xbc, const float* __restrict__ Y,
    unsigned short* __restrict__ V, int count)
{
  int t = blockIdx.x*256 + threadIdx.x;
  if (t >= count*32) return;
  int e = t >> 5, m = t & 31;
  const unsigned short* wr = xbc + (size_t)e*672 + 544 + m;
  float ws[4] = { b2f(wr[0]), b2f(wr[32]), b2f(wr[64]), b2f(wr[96]) };
  const float4* Y4 = (const float4*)(Y + (size_t)e*16);
  float yv[16];
  #pragma unroll
  for (int q=0;q<4;q++){ float4 f=Y4[q]; yv[q*4]=f.x; yv[q*4+1]=f.y; yv[q*4+2]=f.z; yv[q*4+3]=f.w; }
  constexpr int LOFK[16] = {0,1,1,1,2,2,2,2,2,3,3,3,3,3,3,3};
  s8v o0, o1;
  #pragma unroll
  for (int k=0;k<8;k++)  o0[k] = (short)f2b(ws[LOFK[k]]   * yv[k]);
  #pragma unroll
  for (int k=0;k<8;k++)  o1[k] = (short)f2b(ws[LOFK[8+k]] * yv[8+k]);
  s8v* vo = (s8v*)(V + (size_t)e*512 + (size_t)m*16);
  vo[0] = o0; vo[1] = o1;
}

// ---------------- CSR build: scan -> fill (histogram fused into edge_init) ----
__global__ __launch_bounds__(256) void scan_k(
    const int* __restrict__ deg, int* __restrict__ offs, int Nn)
{
  __shared__ int part[256];
  const int t = threadIdx.x;
  const int per = (Nn + 255) / 256;
  int base = t*per;
  int loc[32];
  int s = 0;
  for (int i=0;i<per;i++){ int v = (base+i<Nn)?deg[base+i]:0; loc[i]=s; s+=v; }
  part[t] = s;
  __syncthreads();
  for (int off=1; off<256; off<<=1){
    int v = (t>=off) ? part[t-off] : 0;
    __syncthreads();
    part[t] += v;
    __syncthreads();
  }
  int pre = (t==0) ? 0 : part[t-1];
  for (int i=0;i<per;i++) if (base+i<Nn) offs[base+i] = pre + loc[i];
  if (t==255) offs[Nn] = part[255];
}

__global__ __launch_bounds__(256) void fill_k(
    const int* __restrict__ rcv, int* __restrict__ cursor,
    const int* __restrict__ offs, int* __restrict__ elist, int E)
{
  int e = blockIdx.x*256 + threadIdx.x;
  if (e >= E) return;
  int r = rcv[e];
  int p = atomicAdd(&cursor[r], 1);
  elist[offs[r] + p] = e;
}

// ---------------- env build (w = bf16 cols [512..544) of xb) -------------------
__global__ __launch_bounds__(512) void env_build(
    const unsigned short* __restrict__ xb, const float* __restrict__ Y,
    const int* __restrict__ elist, const int* __restrict__ offs,
    float* __restrict__ nenv)
{
  const int n = blockIdx.x;
  const int j = threadIdx.x;          // 0..511
  const int m = j >> 4, kk = j & 15;
  const int beg = offs[n], end = offs[n+1];
  float acc = 0.f;
  for (int p = beg; p < end; ++p) {
    int e = elist[p];
    acc += b2f(xb[(size_t)e*672 + 512 + m]) * Y[(size_t)e*16 + kk];
  }
  nenv[(size_t)n*512 + j] = acc;
}

// ------------ fused tensor product + V-mix (layer 0; literal-fmac TP) ----------
// Grid-stride over 4 edge-groups per block (persistence: 8192 short blocks ->
// 2048 longer blocks; achieved occupancy was 42% from block churn).
__global__ __launch_bounds__(256, 2) void tp_mix(
    const float* __restrict__ nenv, const int* __restrict__ senders,
    unsigned short* __restrict__ V,
    const float* __restrict__ wm,     // layer slice: [4][32][32]
    unsigned short* __restrict__ xb, int E)
{
  __shared__ float Ts[8][32][18];     // pitch 18: f2v-aligned rows, 2-way bank (free)
  const int tid = threadIdx.x;
  const int le = tid >> 5, m = tid & 31;
  for (int g = 0; g < 4; ++g){
  const int e = (blockIdx.x*4 + g)*8 + le;
  const int s = senders[e];
  float env[16], v[16], acc[16];
  const float4* ne4 = (const float4*)(nenv + (size_t)s*512 + (size_t)m*16);
  #pragma unroll
  for (int q=0;q<4;q++){
    float4 f = ne4[q];
    env[q*4]=f.x; env[q*4+1]=f.y; env[q*4+2]=f.z; env[q*4+3]=f.w;
  }
  const s8v* vv = (const s8v*)(V + (size_t)e*512 + (size_t)m*16);
  s8v v0 = vv[0], v1 = vv[1];
  #pragma unroll
  for (int q=0;q<8;q++){ v[q] = b2f((unsigned short)v0[q]); v[8+q] = b2f((unsigned short)v1[q]); }
  #pragma unroll
  for (int k=0;k<16;k++) acc[k] = 0.f;

  tp_pair<0,0>(env,v,acc); tp_pair<0,1>(env,v,acc); tp_pair<0,2>(env,v,acc); tp_pair<0,3>(env,v,acc);
  tp_pair<1,0>(env,v,acc); tp_pair<1,1>(env,v,acc); tp_pair<1,2>(env,v,acc); tp_pair<1,3>(env,v,acc);
  tp_pair<2,0>(env,v,acc); tp_pair<2,1>(env,v,acc); tp_pair<2,2>(env,v,acc); tp_pair<2,3>(env,v,acc);
  tp_pair<3,0>(env,v,acc); tp_pair<3,1>(env,v,acc); tp_pair<3,2>(env,v,acc); tp_pair<3,3>(env,v,acc);

  xb[(size_t)e*672 + 512 + m] = f2b(acc[0]);   // t0 (TN3 folded into W3V)

  #pragma unroll
  for (int k=0;k<16;k++) Ts[le][m][k] = acc[k];
  // (no barrier: same-wave producer/consumer)
  f2v o2[8];
  #pragma unroll
  for (int kp=0;kp<8;kp++){ o2[kp][0]=0.f; o2[kp][1]=0.f; }
  #pragma unroll
  for (int mm=0; mm<32; mm++) {
    float w0 = wm[        mm*32 + m];
    float w1 = wm[1024 +  mm*32 + m];
    float w2 = wm[2048 +  mm*32 + m];
    float w3 = wm[3072 +  mm*32 + m];
    const f2v* tr = (const f2v*)Ts[le][mm];
    f2v p01; p01[0]=w0; p01[1]=w1;
    f2v p11; p11[0]=w1; p11[1]=w1;
    f2v p22; p22[0]=w2; p22[1]=w2;
    f2v p23; p23[0]=w2; p23[1]=w3;
    f2v p33; p33[0]=w3; p33[1]=w3;
    o2[0] += tr[0]*p01; o2[1] += tr[1]*p11; o2[2] += tr[2]*p22; o2[3] += tr[3]*p22;
    o2[4] += tr[4]*p23; o2[5] += tr[5]*p33; o2[6] += tr[6]*p33; o2[7] += tr[7]*p33;
  }
  s8v oa, ob;
  #pragma unroll
  for (int kp=0;kp<4;kp++){
    oa[2*kp]   = (short)f2b(o2[kp][0]   * 0.17677669529663689f); // 1/sqrt(32)
    oa[2*kp+1] = (short)f2b(o2[kp][1]   * 0.17677669529663689f);
    ob[2*kp]   = (short)f2b(o2[4+kp][0] * 0.17677669529663689f);
    ob[2*kp+1] = (short)f2b(o2[4+kp][1] * 0.17677669529663689f);
  }
  s8v* vo = (s8v*)(V + (size_t)e*512 + (size_t)m*16);
  vo[0] = oa; vo[1] = ob;
  }
}

// ------------ last-layer TP: only l3=0 survives; t0 -> xb bf16 ------------------
// Grid-stride x4 (persistence).
__global__ __launch_bounds__(256) void tp_last(
    const float* __restrict__ nenv, const int* __restrict__ senders,
    const unsigned short* __restrict__ V, unsigned short* __restrict__ xb, int E)
{
  for (int g = 0; g < 4; ++g){
  int t = (blockIdx.x*4 + g)*256 + threadIdx.x;
  int e = t >> 5, m = t & 31;
  if (e >= E) continue;
  int s = senders[e];
  float env[16], v[16], acc[16];
  const float4* ne4 = (const float4*)(nenv + (size_t)s*512 + (size_t)m*16);
  #pragma unroll
  for (int q=0;q<4;q++){
    float4 f = ne4[q];
    env[q*4]=f.x; env[q*4+1]=f.y; env[q*4+2]=f.z; env[q*4+3]=f.w;
  }
  const s8v* vv = (const s8v*)(V + (size_t)e*512 + (size_t)m*16);
  s8v v0 = vv[0], v1 = vv[1];
  #pragma unroll
  for (int q=0;q<8;q++){ v[q] = b2f((unsigned short)v0[q]); v[8+q] = b2f((unsigned short)v1[q]); }
  #pragma unroll
  for (int k=0;k<16;k++) acc[k] = 0.f;
  tp_tri<0,0,0>(env,v,acc); tp_tri<1,1,0>(env,v,acc);
  tp_tri<2,2,0>(env,v,acc); tp_tri<3,3,0>(env,v,acc);
  xb[(size_t)e*672 + 512 + m] = f2b(acc[0]);
  }
}

// -------- fused final output: out[e] = rs512^2 * cut[e] * dot(h[e], fv) --------
__global__ __launch_bounds__(256) void out_fused(
    const unsigned short* __restrict__ h, const float* __restrict__ fv,
    const float* __restrict__ cutv, float* __restrict__ out, int count)
{
  int gw = (blockIdx.x*256 + threadIdx.x) >> 6;
  int lane = threadIdx.x & 63;
  if (gw >= count) return;
  const s8v* xr = (const s8v*)(h + (size_t)gw*512);
  s8v chunk = xr[lane];
  float s = 0.f;
  #pragma unroll
  for (int j=0;j<8;j++) s += b2f((unsigned short)chunk[j]) * fv[lane*8 + j];
  #pragma unroll
  for (int off=32; off; off>>=1) s += __shfl_down(s, off);
  if (lane == 0)
    out[gw] = s * cutv[gw] * (0.044194173824159216f * 0.044194173824159216f);
}

// ---------------- workspace sizing ----------------
static inline size_t alup(size_t b){ return (b + 255) & ~(size_t)255; }
static size_t need_bytes(int E, int N, int chd){
  size_t s = 0;
  s += alup((size_t)E*16*4);            // Yb
  s += alup((size_t)E*4);               // cutb
  s += alup((size_t)N*512*4);           // nenv
  s += alup((size_t)E*64*2);            // feat
  s += alup((size_t)chd*512*2);         // cbuf
  s += alup((size_t)E*512*2);           // Vb
  s += alup((size_t)E*672*2);           // xb (x | w/t0 | wi)
  s += alup((size_t)512*64*2);          // we0T
  s += alup((size_t)768*512*2);         // weF (we1T + fused wenv0 + fused winit)
  s += alup((size_t)128*512*2);         // winT
  s += alup((size_t)2*32*512*2);        // wenvT
  s += alup((size_t)2*512*576*2);       // wl0T (Kpad 576)
  s += alup((size_t)640*512*2);         // wl1F (wlat1T_l0 + fused wenv1)
  s += alup((size_t)512*512*2);         // we1c
  s += alup((size_t)512*512*2);         // wl1c
  s += alup(512*4);                     // fv
  s += alup((size_t)N*4);               // deg
  s += alup(((size_t)N+1)*4);           // offs
  s += alup((size_t)N*4);               // cursor
  s += alup((size_t)E*4);               // elist
  return s;
}

// ---------------- launch ----------------
extern "C" void kernel_launch(void* const* d_in, const int* in_sizes, int n_in,
                              void* d_out, int out_size, void* d_ws, size_t ws_size,
                              hipStream_t stream)
{
  const float* node_attrs = (const float*)d_in[0];
  const float* vectors    = (const float*)d_in[1];
  const float* we0        = (const float*)d_in[2];
  const float* we1        = (const float*)d_in[3];
  const float* winit      = (const float*)d_in[4];
  const float* wenv       = (const float*)d_in[5];
  const float* wlat0      = (const float*)d_in[6];
  const float* wlat1      = (const float*)d_in[7];
  const float* wmix       = (const float*)d_in[8];
  const float* wout       = (const float*)d_in[9];
  const int*   senders    = (const int*)d_in[10];
  const int*   receivers  = (const int*)d_in[11];
  float* out = (float*)d_out;
  const int E = in_sizes[1] / 3;
  const int N = in_sizes[0] / 16;

  int CHD = -1;
  const int tiers[4] = {E, E/2, E/4, CH};
  for (int i=0;i<4;i++){
    if (tiers[i] >= CH && need_bytes(E, N, tiers[i]) <= ws_size){ CHD = tiers[i]; break; }
  }
  if (CHD < 0) return;                  // diagnostic clean fail

  char* base = (char*)d_ws;
  size_t off = 0;
  auto carve = [&](size_t b) -> char* { char* p = base + off; off += alup(b); return p; };
  float*          Yb    = (float*)carve((size_t)E*16*4);
  float*          cutb  = (float*)carve((size_t)E*4);
  float*          nenv  = (float*)carve((size_t)N*512*4);
  unsigned short* feat  = (unsigned short*)carve((size_t)E*64*2);
  unsigned short* cbuf  = (unsigned short*)carve((size_t)CHD*512*2);
  unsigned short* Vb    = (unsigned short*)carve((size_t)E*512*2);
  unsigned short* xb    = (unsigned short*)carve((size_t)E*672*2);
  unsigned short* we0T  = (unsigned short*)carve((size_t)512*64*2);
  unsigned short* weF   = (unsigned short*)carve((size_t)768*512*2);
  unsigned short* winT  = (unsigned short*)carve((size_t)128*512*2);
  unsigned short* wenvT = (unsigned short*)carve((size_t)2*32*512*2);
  unsigned short* wl0T  = (unsigned short*)carve((size_t)2*512*576*2);
  unsigned short* wl1F  = (unsigned short*)carve((size_t)640*512*2);
  unsigned short* we1c  = (unsigned short*)carve((size_t)512*512*2);
  unsigned short* wl1c  = (unsigned short*)carve((size_t)512*512*2);
  float*          fv    = (float*)carve(512*4);
  int*            deg   = (int*)carve((size_t)N*4);
  int*            offs  = (int*)carve(((size_t)N+1)*4);
  int*            cursor= (int*)carve((size_t)N*4);
  int*            elist = (int*)carve((size_t)E*4);

  const float rs40  = 0.15811388300841897f;  // 1/sqrt(40)
  const float rs512 = 0.044194173824159216f; // 1/sqrt(512)
  const float rs544 = 0.042874646285627205f; // 1/sqrt(544)

  dim3 blk(256);
  // zero CSR scratch first (edge_init's fused histogram needs deg=0)
  hipMemsetAsync(deg, 0, (size_t)N*4, stream);
  hipMemsetAsync(cursor, 0, (size_t)N*4, stream);

  // batched weight conversion (one dispatch, 10 segments)
  WDesc wd;
  auto seg = [&](int i, const float* W, unsigned short* WT, int K, int Nn, int Kpad, int trans){
    int elems = trans ? Nn*Kpad : K*Nn;
    wd.s[i] = { W, WT, K, Nn, Kpad, (elems + 255)/256, trans };
  };
  seg(0, we0,   we0T, 40, 512, 64, 1);
  seg(1, we1,   weF,  512, 512, 512, 1);                                  // rows 0..512
  seg(2, winit, winT, 512, 128, 512, 1);
  seg(3, wenv,                  wenvT,                  512, 32, 512, 1);
  seg(4, wenv + (size_t)512*32, wenvT + (size_t)32*512, 512, 32, 512, 1);
  seg(5, wlat0,                   wl0T,                   544, 512, 576, 1);
  seg(6, wlat0 + (size_t)544*512, wl0T + (size_t)512*576, 544, 512, 576, 1);
  seg(7, wlat1,                   wl1F,  512, 512, 512, 1);               // rows 0..512
  seg(8, we1,   we1c, 512, 512, 512, 0);                                  // straight copy
  seg(9, wlat1, wl1c, 512, 512, 512, 0);
  int totblk = 0;
  for (int i=0;i<10;i++) totblk += wd.s[i].nblk;
  wconv_all<<<totblk, blk, 0, stream>>>(wd);
  wfuse_vec<<<2, blk, 0, stream>>>(wlat1 + (size_t)512*512, wout, fv);

  // weight-fusion GEMMs (write transposed, bf16):
  gemm_mfma<64,unsigned short,false,false,true><<<dim3(1,4), blk, 0, stream>>>(
      we1c, 512, 512, wenvT, 512, weF + (size_t)512*512, 512, nullptr, 32, 512, rs512*0.25f);
  gemm_mfma<128,unsigned short,false,false,true><<<dim3(1,4), blk, 0, stream>>>(
      we1c, 512, 512, winT, 512, weF + (size_t)544*512, 512, nullptr, 128, 512, rs512);
  gemm_mfma<64,unsigned short,false,false,true><<<dim3(1,4), blk, 0, stream>>>(
      wl1c, 512, 512, wenvT + (size_t)32*512, 512, wl1F + (size_t)512*512, 512, nullptr, 32, 512, rs512*0.25f);

  edge_init<<<E/256, blk, 0, stream>>>(vectors, node_attrs, senders, receivers, feat, Yb, cutb, deg, E);

  // CSR of receivers (histogram fused into edge_init)
  scan_k<<<1, blk, 0, stream>>>(deg, offs, N);
  fill_k<<<(E+255)/256, blk, 0, stream>>>(receivers, cursor, offs, elist, E);

  // edge embedding: feat -> h (silu) -> [x | w0 | wi] (cut) ; V init
  for (int c0 = 0; c0 < E; c0 += CHD) {
    gemm_mfma<128,unsigned short,true,false><<<dim3(4, CHD/128), blk, 0, stream>>>(
        feat + (size_t)c0*64, 64, 64, we0T, 64, cbuf, 512, nullptr, 512, 64, rs40);
    gemm_mfma<128,unsigned short,false,true><<<dim3(6, CHD/128), blk, 0, stream>>>(
        cbuf, 512, 512, weF, 512, xb + (size_t)c0*672, 672, cutb + c0, 672, 512, rs512);
    vbuild<<<(CHD*32)/256, blk, 0, stream>>>(xb + (size_t)c0*672, Yb + (size_t)c0*16, Vb + (size_t)c0*512, CHD);
  }

  for (int layer = 0; layer < 2; ++layer) {
    env_build<<<N, 512, 0, stream>>>(xb, Yb, elist, offs, nenv);
    if (layer == 0)
      tp_mix<<<E/32, blk, 0, stream>>>(nenv, senders, Vb,
          wmix, xb, E);
    else
      tp_last<<<(E*32)/1024, blk, 0, stream>>>(nenv, senders, Vb, xb, E);
    for (int c0 = 0; c0 < E; c0 += CHD) {
      // lat0: pure K=576 GEMM over [x | t0 | (dead wi, zero-weighted)]
      gemm_mfma<128,unsigned short,true,false><<<dim3(4, CHD/128), blk, 0, stream>>>(
          xb + (size_t)c0*672, 672, 576, wl0T + (size_t)layer*512*576, 576,
          cbuf, 512, nullptr, 512, 576, rs544);
      if (layer == 0)
        // lat1 + fused wenv of next layer
        gemm_mfma<128,unsigned short,false,true><<<dim3(5, CHD/128), blk, 0, stream>>>(
            cbuf, 512, 512, wl1F, 512, xb + (size_t)c0*672, 672, cutb + c0, 544, 512, rs512);
      else
        // final lat1 GEMM eliminated: out = rs512^2 * cut * <h, wlat1@wout>
        out_fused<<<CHD/4, blk, 0, stream>>>(cbuf, fv, cutb + c0, out + c0, CHD);
    }
  }
}

// Round 16
// 631.657 us; speedup vs baseline: 1.1342x; 1.1342x over previous
//
#include <hip/hip_runtime.h>
#include <math.h>
#include <type_traits>

typedef __attribute__((ext_vector_type(8))) short s8v;   // 8 bf16 (4 VGPR)
typedef __attribute__((ext_vector_type(4))) float f4v;   // MFMA acc
typedef __attribute__((ext_vector_type(2))) float f2v;   // packed f32 pair

#define CH 8192

// ---------------- bf16 bit helpers ----------------
__device__ inline float b2f(unsigned short u){ return __uint_as_float(((unsigned)u)<<16); }
__device__ inline unsigned short f2b(float f){
  unsigned u = __float_as_uint(f);
  return (unsigned short)((u + 0x7FFFu + ((u>>16)&1u)) >> 16);   // RNE
}
__device__ inline void stC(float* p, float v){ *p = v; }
__device__ inline void stC(unsigned short* p, float v){ *p = f2b(v); }

// async global->LDS, 16B per lane; lds base must be wave-uniform
__device__ __forceinline__ void gl16(const void* g, void* l){
  __builtin_amdgcn_global_load_lds(
      (const __attribute__((address_space(1))) unsigned*)g,
      (__attribute__((address_space(3))) unsigned*)l, 16, 0, 0);
}

// ================= compile-time real Wigner (CG) tables =================
constexpr double FCT[11] = {1.,1.,2.,6.,24.,120.,720.,5040.,40320.,362880.,3628800.};
constexpr double csqrt_c(double x){
  double g = x > 1.0 ? x : 1.0;
  for (int i=0;i<60;i++) g = 0.5*(g + x/g);
  return g;
}
struct CD { double re, im; };
constexpr CD cmulc(CD a, CD b){ return {a.re*b.re - a.im*b.im, a.re*b.im + a.im*b.re}; }

constexpr double su2cg_c(int j1,int j2,int j3,int m1,int m2,int m3){
  if (m1+m2 != m3) return 0.0;
  double pref = csqrt_c((double)(2*j3+1) * FCT[j1+j2-j3]*FCT[j1-j2+j3]*FCT[-j1+j2+j3]/FCT[j1+j2+j3+1]
              * FCT[j3+m3]*FCT[j3-m3]*FCT[j1-m1]*FCT[j1+m1]*FCT[j2-m2]*FCT[j2+m2]);
  int kmin = 0;
  if (j2-j3-m1 > kmin) kmin = j2-j3-m1;
  if (j1-j3+m2 > kmin) kmin = j1-j3+m2;
  int kmax = j1+j2-j3;
  if (j1-m1 < kmax) kmax = j1-m1;
  if (j2+m2 < kmax) kmax = j2+m2;
  double s = 0.0;
  for (int k=kmin;k<=kmax;k++){
    double t = 1.0/(FCT[k]*FCT[j1+j2-j3-k]*FCT[j1-m1-k]*FCT[j2+m2-k]*FCT[j3-j2+m1+k]*FCT[j3-j1-m2+k]);
    s += (k&1) ? -t : t;
  }
  return pref*s;
}

constexpr CD qelem_c(int l, int i, int j){
  int m = i - l;
  const double is2 = 0.70710678118654752440;
  double re=0.0, im=0.0;
  if (m < 0){
    if (j == l - m) re = is2;
    else if (j == l + m) im = -is2;
  } else if (m == 0){
    if (j == l) re = 1.0;
  } else {
    double sgn = (m & 1) ? -1.0 : 1.0;
    if (j == l + m) re = sgn*is2;
    else if (j == l - m) im = sgn*is2;
  }
  CD r{};
  switch (l & 3){                    // (-i)^l
    case 0: r = {re, im}; break;
    case 1: r = {im, -re}; break;
    case 2: r = {-re, -im}; break;
    default: r = {-im, re}; break;
  }
  return r;
}

// path-count normalization per l3: n = {4,9,11,10}
constexpr double TN3[4] = {0.5, 1.0/3.0, 0.30151134457776363, 0.31622776601683794};

template<int L1,int L2,int L3>
struct TriVals { float v[(2*L1+1)*(2*L2+1)*(2*L3+1)]; };

template<int L1,int L2,int L3>
constexpr TriVals<L1,L2,L3> make_tri(){
  constexpr int n1=2*L1+1, n2=2*L2+1, n3=2*L3+1;
  double cg[n1*n2*n3] = {};
  for (int a=0;a<n1;a++)
    for (int b=0;b<n2;b++)
      for (int c=0;c<n3;c++)
        cg[(a*n2+b)*n3+c] = su2cg_c(L1,L2,L3, a-L1, b-L2, c-L3);
  double cr[n1*n2*n3] = {};
  double ci[n1*n2*n3] = {};
  for (int i=0;i<n1;i++)
   for (int j=0;j<n2;j++)
    for (int k=0;k<n3;k++){
      double sre=0.0, sim=0.0;
      for (int a=0;a<n1;a++){
        CD q1 = qelem_c(L1,i,a);
        if (q1.re==0.0 && q1.im==0.0) continue;
        for (int b=0;b<n2;b++){
          CD q2 = qelem_c(L2,j,b);
          if (q2.re==0.0 && q2.im==0.0) continue;
          CD q12 = cmulc(q1,q2);
          for (int c=0;c<n3;c++){
            double g = cg[(a*n2+b)*n3+c];
            if (g == 0.0) continue;
            CD q3 = qelem_c(L3,k,c);
            CD q3c{q3.re, -q3.im};
            CD q = cmulc(q12,q3c);
            sre += q.re*g; sim += q.im*g;
          }
        }
      }
      cr[(i*n2+j)*n3+k]=sre; ci[(i*n2+j)*n3+k]=sim;
    }
  double nr=0.0, ni=0.0;
  for (int i=0;i<n1*n2*n3;i++){ nr += cr[i]*cr[i]; ni += ci[i]*ci[i]; }
  bool pr = nr >= ni;
  double nn = csqrt_c(pr ? nr : ni);
  TriVals<L1,L2,L3> t{};
  for (int i=0;i<n1*n2*n3;i++)
    t.v[i] = (float)(((pr ? cr[i] : ci[i]) / nn) * TN3[L3]);
  return t;
}

template<int L1,int L2,int L3>
constexpr TriVals<L1,L2,L3> W3V = make_tri<L1,L2,L3>();

constexpr int LOFFC[4] = {0,1,4,9};

// ---- FMA with inline 32-bit literal (VOP2 v_fmac_f32, src0=literal: free) ----
template<int WB>
__device__ __forceinline__ void fmac_lit(float& a, float p){
  asm("v_fmac_f32 %0, %2, %1" : "+v"(a) : "v"(p), "i"(WB));
}

// static-for
template<int I, int N, typename F>
__device__ __forceinline__ void sfor(F&& f){
  if constexpr (I < N){
    f(std::integral_constant<int,I>{});
    sfor<I+1,N>(static_cast<F&&>(f));
  }
}

// grouped TP: one (L1,L2) pair -> each product computed ONCE, all valid l3 emitted
template<int L1,int L2>
__device__ __forceinline__ void tp_pair(const float* __restrict__ env,
                                        const float* __restrict__ v,
                                        float* __restrict__ acc){
  sfor<0,2*L1+1>([&](auto K1c){
    constexpr int k1 = decltype(K1c)::value;
    sfor<0,2*L2+1>([&](auto K2c){
      constexpr int k2 = decltype(K2c)::value;
      float p = env[LOFFC[L1]+k1] * v[LOFFC[L2]+k2];
      sfor<0,4>([&](auto L3c){
        constexpr int l3 = decltype(L3c)::value;
        constexpr int lo = (L1>L2)?(L1-L2):(L2-L1);
        if constexpr (l3 >= lo && l3 <= L1+L2){
          sfor<0,2*l3+1>([&](auto K3c){
            constexpr int k3 = decltype(K3c)::value;
            constexpr float w = W3V<L1,L2,l3>.v[(k1*(2*L2+1)+k2)*(2*l3+1)+k3];
            if constexpr (w != 0.f){
              fmac_lit<__builtin_bit_cast(int, w)>(acc[LOFFC[l3]+k3], p);
            }
          });
        }
      });
    });
  });
}

// scalar per-triple variant (tp_last, l3=0 only: tiny)
template<int L1,int L2,int L3>
__device__ __forceinline__ void tp_tri(const float* __restrict__ env,
                                       const float* __restrict__ v,
                                       float* __restrict__ acc){
  constexpr int n1=2*L1+1, n2=2*L2+1, n3=2*L3+1;
  #pragma unroll
  for (int k1=0;k1<n1;k1++)
    #pragma unroll
    for (int k2=0;k2<n2;k2++){
      float p = env[LOFFC[L1]+k1] * v[LOFFC[L2]+k2];
      #pragma unroll
      for (int k3=0;k3<n3;k3++){
        float w = W3V<L1,L2,L3>.v[(k1*n2+k2)*n3+k3];
        if (w != 0.f) acc[LOFFC[L3]+k3] += w * p;
      }
    }
}

// ---------------- batched weight convert (+optional transpose) ----------------
struct WSeg { const float* W; unsigned short* WT; int K, N, Kpad, nblk, trans; };
struct WDesc { WSeg s[10]; };
__global__ __launch_bounds__(256) void wconv_all(WDesc d){
  int b = blockIdx.x;
  int seg = 0;
  while (b >= d.s[seg].nblk){ b -= d.s[seg].nblk; ++seg; }
  const WSeg w = d.s[seg];
  int idx = b*256 + threadIdx.x;
  if (w.trans){
    if (idx >= w.N*w.Kpad) return;
    int n = idx / w.Kpad, k = idx - n*w.Kpad;
    w.WT[idx] = (k < w.K) ? f2b(w.W[(size_t)k*w.N + n]) : (unsigned short)0;
  } else {
    if (idx >= w.K*w.N) return;
    w.WT[idx] = f2b(w.W[idx]);
  }
}

// ---------------- fused output vector: fv = wlat1_l1 @ wout (fp32) -------------
__global__ __launch_bounds__(256) void wfuse_vec(
    const float* __restrict__ wl1_l1, const float* __restrict__ wout,
    float* __restrict__ fv)
{
  int k = blockIdx.x*256 + threadIdx.x;
  if (k >= 512) return;
  float s = 0.f;
  for (int n=0;n<512;n++) s += wl1_l1[(size_t)k*512 + n] * wout[n];
  fv[k] = s;
}

// ---------------- edge geometry + receiver histogram ----------------
__global__ __launch_bounds__(256) void edge_init(
    const float* __restrict__ vec, const float* __restrict__ na,
    const int* __restrict__ snd, const int* __restrict__ rcv,
    unsigned short* __restrict__ feat, float* __restrict__ Y, float* __restrict__ cutb,
    int* __restrict__ deg, int E)
{
  int e = blockIdx.x*256 + threadIdx.x;
  if (e >= E) return;
  float vx = vec[(size_t)e*3], vy = vec[(size_t)e*3+1], vz = vec[(size_t)e*3+2];
  float d = sqrtf(vx*vx + vy*vy + vz*vz);
  float inv = 1.f/(d + 1e-9f);
  float x = vx*inv, y = vy*inv, z = vz*inv;
  float dc = d * 0.4f;               // d / 2.5
  float dci = 1.f/(dc + 1e-9f);
  unsigned short* f = feat + (size_t)e*64;
  #pragma unroll
  for (int k=1;k<=8;k++)
    f[k-1] = f2b(1.41421356237309515f * sinf(dc * 3.14159265358979323846f * k) * dci);
  int s = snd[e], r = rcv[e];
  atomicAdd(&deg[r], 1);             // CSR histogram (fused; deg pre-zeroed)
  #pragma unroll
  for (int i=0;i<16;i++) f[8+i]  = f2b(na[(size_t)s*16+i]);
  #pragma unroll
  for (int i=0;i<16;i++) f[24+i] = f2b(na[(size_t)r*16+i]);
  #pragma unroll
  for (int i=40;i<64;i++) f[i] = 0;
  float cv = 0.f;
  if (dc < 1.f){
    float d2 = dc*dc; float d6 = d2*d2*d2; float d7 = d6*dc; float d8 = d7*dc;
    cv = 1.f - 28.f*d6 + 48.f*d7 - 21.f*d8;
  }
  cutb[e] = cv;
  float* Ye = Y + (size_t)e*16;
  const float s3=1.7320508075688772f, s5=2.2360679774997896f, s15=3.8729833462074170f;
  Ye[0] = 1.f;
  Ye[1] = s3*y; Ye[2] = s3*z; Ye[3] = s3*x;
  Ye[4] = s15*x*y; Ye[5] = s15*y*z; Ye[6] = 0.5f*s5*(3.f*z*z-1.f);
  Ye[7] = s15*x*z; Ye[8] = 0.5f*s15*(x*x - y*y);
  const float c1=2.0916500663351889f, c2=10.246950765959598f, c3=1.6201851746019649f, c4=1.3228756555322954f;
  Ye[9]  = c1*y*(3.f*x*x - y*y);
  Ye[10] = c2*x*y*z;
  Ye[11] = c3*y*(5.f*z*z - 1.f);
  Ye[12] = c4*z*(5.f*z*z - 3.f);
  Ye[13] = c3*x*(5.f*z*z - 1.f);
  Ye[14] = 0.5f*c2*z*(x*x - y*y);
  Ye[15] = c1*x*(x*x - 3.f*y*y);
}

// ---------------- MFMA bf16 GEMM with global_load_lds staging ------------------
// TSTORE: write C transposed (C[col*ldc+row]) — used for weight-fusion GEMMs.
template<int NT, typename TC, bool SILU, bool CUT, bool TSTORE=false>
__global__ __launch_bounds__(256) void gemm_mfma(
    const unsigned short* __restrict__ A, int lda, int K1,
    const unsigned short* __restrict__ WT, int ldw,
    TC* __restrict__ C, int ldc,
    const float* __restrict__ cutv,
    int N, int K, float scale)
{
  constexpr int NB = NT/16;
  __shared__ s8v As8[128*8];
  __shared__ s8v Bs8[NT*8];
  const int tid = threadIdx.x;
  const int wid = tid >> 6, lane = tid & 63;
  const int r15 = lane & 15, kg = lane >> 4;
  const int col0 = blockIdx.x * NT;
  const int row0 = blockIdx.y * 128;
  f4v acc[2][NB] = {};

  auto compute = [&](){
    #pragma unroll
    for (int s = 0; s < 2; s++) {
      const int cb = s*4 + kg;
      const int cx = cb ^ (r15 & 7);
      s8v a0 = As8[(wid*32      + r15)*8 + cx];
      s8v a1 = As8[(wid*32 + 16 + r15)*8 + cx];
      #pragma unroll
      for (int j = 0; j < NB; j++) {
        s8v b = Bs8[(j*16 + r15)*8 + cx];
        acc[0][j] = __builtin_amdgcn_mfma_f32_16x16x32_bf16(a0, b, acc[0][j], 0,0,0);
        acc[1][j] = __builtin_amdgcn_mfma_f32_16x16x32_bf16(a1, b, acc[1][j], 0,0,0);
      }
    }
  };

  for (int k0 = 0; k0 < K; k0 += 64) {
    #pragma unroll
    for (int i = 0; i < 4; i++) {       // A tile: 1024 segs of 16B
      int seg = i*256 + tid;
      int r = seg >> 3, ks = seg & 7;
      int ksx = ks ^ (r & 7);
      gl16(A + (size_t)(row0+r)*lda + k0 + ksx*8, &As8[i*256 + (tid & ~63)]);
    }
    #pragma unroll
    for (int i = 0; i < NT/32; i++) {   // B tile: NT*8 segs
      int seg = i*256 + tid;
      int n = seg >> 3, ks = seg & 7;
      int ksx = ks ^ (n & 7);
      gl16(WT + (size_t)(col0+n)*ldw + k0 + ksx*8, &Bs8[i*256 + (tid & ~63)]);
    }
    __syncthreads();
    compute();
    __syncthreads();
  }
  // epilogue: C/D layout col = lane&15, row = (lane>>4)*4 + j
  #pragma unroll
  for (int g=0; g<2; g++) {
    #pragma unroll
    for (int c=0; c<NB; c++) {
      int col = col0 + c*16 + r15;
      if (col >= N) continue;
      #pragma unroll
      for (int j=0;j<4;j++) {
        int row = row0 + wid*32 + g*16 + kg*4 + j;
        float v = acc[g][c][j] * scale;
        if (SILU) v = v / (1.f + __expf(-v));
        if (CUT)  v *= cutv[row];
        if (TSTORE) stC(&C[(size_t)col*ldc + row], v);
        else        stC(&C[(size_t)row*ldc + col], v);
      }
    }
  }
}

// ---------------- V init: thread per (e,m); wi = xb cols [544..672) ------------
__global__ __launch_bounds__(256) void vbuild(
    const unsigned short* __restrict__ xbc, const float* __restrict__ Y,
    unsigned short* __restrict__ V, int count)
{
  int t = blockIdx.x*256 + threadIdx.x;
  if (t >= count*32) return;
  int e = t >> 5, m = t & 31;
  const unsigned short* wr = xbc + (size_t)e*672 + 544 + m;
  float ws[4] = { b2f(wr[0]), b2f(wr[32]), b2f(wr[64]), b2f(wr[96]) };
  const float4* Y4 = (const float4*)(Y + (size_t)e*16);
  float yv[16];
  #pragma unroll
  for (int q=0;q<4;q++){ float4 f=Y4[q]; yv[q*4]=f.x; yv[q*4+1]=f.y; yv[q*4+2]=f.z; yv[q*4+3]=f.w; }
  constexpr int LOFK[16] = {0,1,1,1,2,2,2,2,2,3,3,3,3,3,3,3};
  s8v o0, o1;
  #pragma unroll
  for (int k=0;k<8;k++)  o0[k] = (short)f2b(ws[LOFK[k]]   * yv[k]);
  #pragma unroll
  for (int k=0;k<8;k++)  o1[k] = (short)f2b(ws[LOFK[8+k]] * yv[8+k]);
  s8v* vo = (s8v*)(V + (size_t)e*512 + (size_t)m*16);
  vo[0] = o0; vo[1] = o1;
}

// ---------------- CSR build: scan -> fill (histogram fused into edge_init) ----
__global__ __launch_bounds__(256) void scan_k(
    const int* __restrict__ deg, int* __restrict__ offs, int Nn)
{
  __shared__ int part[256];
  const int t = threadIdx.x;
  const int per = (Nn + 255) / 256;
  int base = t*per;
  int loc[32];
  int s = 0;
  for (int i=0;i<per;i++){ int v = (base+i<Nn)?deg[base+i]:0; loc[i]=s; s+=v; }
  part[t] = s;
  __syncthreads();
  for (int off=1; off<256; off<<=1){
    int v = (t>=off) ? part[t-off] : 0;
    __syncthreads();
    part[t] += v;
    __syncthreads();
  }
  int pre = (t==0) ? 0 : part[t-1];
  for (int i=0;i<per;i++) if (base+i<Nn) offs[base+i] = pre + loc[i];
  if (t==255) offs[Nn] = part[255];
}

__global__ __launch_bounds__(256) void fill_k(
    const int* __restrict__ rcv, int* __restrict__ cursor,
    const int* __restrict__ offs, int* __restrict__ elist, int E)
{
  int e = blockIdx.x*256 + threadIdx.x;
  if (e >= E) return;
  int r = rcv[e];
  int p = atomicAdd(&cursor[r], 1);
  elist[offs[r] + p] = e;
}

// ---------------- env build (w = bf16 cols [512..544) of xb) -------------------
__global__ __launch_bounds__(512) void env_build(
    const unsigned short* __restrict__ xb, const float* __restrict__ Y,
    const int* __restrict__ elist, const int* __restrict__ offs,
    float* __restrict__ nenv)
{
  const int n = blockIdx.x;
  const int j = threadIdx.x;          // 0..511
  const int m = j >> 4, kk = j & 15;
  const int beg = offs[n], end = offs[n+1];
  float acc = 0.f;
  for (int p = beg; p < end; ++p) {
    int e = elist[p];
    acc += b2f(xb[(size_t)e*672 + 512 + m]) * Y[(size_t)e*16 + kk];
  }
  nenv[(size_t)n*512 + j] = acc;
}

// ------------ fused tensor product + V-mix (layer 0; literal-fmac TP) ----------
// R14-measured codegen (VGPR 60, ~118us). Do NOT restructure: both the float4
// wm-table variant (R11) and the grid-stride persistent variant (R15) perturbed
// regalloc (32-VGPR spill / 128-VGPR bloat) and cost +45..+87us.
__global__ __launch_bounds__(256, 2) void tp_mix(
    const float* __restrict__ nenv, const int* __restrict__ senders,
    unsigned short* __restrict__ V,
    const float* __restrict__ wm,     // layer slice: [4][32][32]
    unsigned short* __restrict__ xb, int E)
{
  __shared__ float Ts[8][32][18];     // pitch 18: f2v-aligned rows, 2-way bank (free)
  const int tid = threadIdx.x;
  const int le = tid >> 5, m = tid & 31;
  const int e = blockIdx.x*8 + le;
  const int s = senders[e];
  float env[16], v[16], acc[16];
  const float4* ne4 = (const float4*)(nenv + (size_t)s*512 + (size_t)m*16);
  #pragma unroll
  for (int q=0;q<4;q++){
    float4 f = ne4[q];
    env[q*4]=f.x; env[q*4+1]=f.y; env[q*4+2]=f.z; env[q*4+3]=f.w;
  }
  const s8v* vv = (const s8v*)(V + (size_t)e*512 + (size_t)m*16);
  s8v v0 = vv[0], v1 = vv[1];
  #pragma unroll
  for (int q=0;q<8;q++){ v[q] = b2f((unsigned short)v0[q]); v[8+q] = b2f((unsigned short)v1[q]); }
  #pragma unroll
  for (int k=0;k<16;k++) acc[k] = 0.f;

  tp_pair<0,0>(env,v,acc); tp_pair<0,1>(env,v,acc); tp_pair<0,2>(env,v,acc); tp_pair<0,3>(env,v,acc);
  tp_pair<1,0>(env,v,acc); tp_pair<1,1>(env,v,acc); tp_pair<1,2>(env,v,acc); tp_pair<1,3>(env,v,acc);
  tp_pair<2,0>(env,v,acc); tp_pair<2,1>(env,v,acc); tp_pair<2,2>(env,v,acc); tp_pair<2,3>(env,v,acc);
  tp_pair<3,0>(env,v,acc); tp_pair<3,1>(env,v,acc); tp_pair<3,2>(env,v,acc); tp_pair<3,3>(env,v,acc);

  xb[(size_t)e*672 + 512 + m] = f2b(acc[0]);   // t0 (TN3 folded into W3V)

  #pragma unroll
  for (int k=0;k<16;k++) Ts[le][m][k] = acc[k];
  // (no barrier: same-wave producer/consumer)
  f2v o2[8];
  #pragma unroll
  for (int kp=0;kp<8;kp++){ o2[kp][0]=0.f; o2[kp][1]=0.f; }
  #pragma unroll
  for (int mm=0; mm<32; mm++) {
    float w0 = wm[        mm*32 + m];
    float w1 = wm[1024 +  mm*32 + m];
    float w2 = wm[2048 +  mm*32 + m];
    float w3 = wm[3072 +  mm*32 + m];
    const f2v* tr = (const f2v*)Ts[le][mm];
    f2v p01; p01[0]=w0; p01[1]=w1;
    f2v p11; p11[0]=w1; p11[1]=w1;
    f2v p22; p22[0]=w2; p22[1]=w2;
    f2v p23; p23[0]=w2; p23[1]=w3;
    f2v p33; p33[0]=w3; p33[1]=w3;
    o2[0] += tr[0]*p01; o2[1] += tr[1]*p11; o2[2] += tr[2]*p22; o2[3] += tr[3]*p22;
    o2[4] += tr[4]*p23; o2[5] += tr[5]*p33; o2[6] += tr[6]*p33; o2[7] += tr[7]*p33;
  }
  s8v oa, ob;
  #pragma unroll
  for (int kp=0;kp<4;kp++){
    oa[2*kp]   = (short)f2b(o2[kp][0]   * 0.17677669529663689f); // 1/sqrt(32)
    oa[2*kp+1] = (short)f2b(o2[kp][1]   * 0.17677669529663689f);
    ob[2*kp]   = (short)f2b(o2[4+kp][0] * 0.17677669529663689f);
    ob[2*kp+1] = (short)f2b(o2[4+kp][1] * 0.17677669529663689f);
  }
  s8v* vo = (s8v*)(V + (size_t)e*512 + (size_t)m*16);
  vo[0] = oa; vo[1] = ob;
}

// ------------ last-layer TP: only l3=0 survives; t0 -> xb bf16 ------------------
__global__ __launch_bounds__(256) void tp_last(
    const float* __restrict__ nenv, const int* __restrict__ senders,
    const unsigned short* __restrict__ V, unsigned short* __restrict__ xb, int E)
{
  int t = blockIdx.x*256 + threadIdx.x;
  int e = t >> 5, m = t & 31;
  if (e >= E) return;
  int s = senders[e];
  float env[16], v[16], acc[16];
  const float4* ne4 = (const float4*)(nenv + (size_t)s*512 + (size_t)m*16);
  #pragma unroll
  for (int q=0;q<4;q++){
    float4 f = ne4[q];
    env[q*4]=f.x; env[q*4+1]=f.y; env[q*4+2]=f.z; env[q*4+3]=f.w;
  }
  const s8v* vv = (const s8v*)(V + (size_t)e*512 + (size_t)m*16);
  s8v v0 = vv[0], v1 = vv[1];
  #pragma unroll
  for (int q=0;q<8;q++){ v[q] = b2f((unsigned short)v0[q]); v[8+q] = b2f((unsigned short)v1[q]); }
  #pragma unroll
  for (int k=0;k<16;k++) acc[k] = 0.f;
  tp_tri<0,0,0>(env,v,acc); tp_tri<1,1,0>(env,v,acc);
  tp_tri<2,2,0>(env,v,acc); tp_tri<3,3,0>(env,v,acc);
  xb[(size_t)e*672 + 512 + m] = f2b(acc[0]);
}

// -------- fused final output: out[e] = rs512^2 * cut[e] * dot(h[e], fv) --------
__global__ __launch_bounds__(256) void out_fused(
    const unsigned short* __restrict__ h, const float* __restrict__ fv,
    const float* __restrict__ cutv, float* __restrict__ out, int count)
{
  int gw = (blockIdx.x*256 + threadIdx.x) >> 6;
  int lane = threadIdx.x & 63;
  if (gw >= count) return;
  const s8v* xr = (const s8v*)(h + (size_t)gw*512);
  s8v chunk = xr[lane];
  float s = 0.f;
  #pragma unroll
  for (int j=0;j<8;j++) s += b2f((unsigned short)chunk[j]) * fv[lane*8 + j];
  #pragma unroll
  for (int off=32; off; off>>=1) s += __shfl_down(s, off);
  if (lane == 0)
    out[gw] = s * cutv[gw] * (0.044194173824159216f * 0.044194173824159216f);
}

// ---------------- workspace sizing ----------------
static inline size_t alup(size_t b){ return (b + 255) & ~(size_t)255; }
static size_t need_bytes(int E, int N, int chd){
  size_t s = 0;
  s += alup((size_t)E*16*4);            // Yb
  s += alup((size_t)E*4);               // cutb
  s += alup((size_t)N*512*4);           // nenv
  s += alup((size_t)E*64*2);            // feat
  s += alup((size_t)chd*512*2);         // cbuf
  s += alup((size_t)E*512*2);           // Vb
  s += alup((size_t)E*672*2);           // xb (x | w/t0 | wi)
  s += alup((size_t)512*64*2);          // we0T
  s += alup((size_t)768*512*2);         // weF (we1T + fused wenv0 + fused winit)
  s += alup((size_t)128*512*2);         // winT
  s += alup((size_t)2*32*512*2);        // wenvT
  s += alup((size_t)2*512*576*2);       // wl0T (Kpad 576)
  s += alup((size_t)640*512*2);         // wl1F (wlat1T_l0 + fused wenv1)
  s += alup((size_t)512*512*2);         // we1c
  s += alup((size_t)512*512*2);         // wl1c
  s += alup(512*4);                     // fv
  s += alup((size_t)N*4);               // deg
  s += alup(((size_t)N+1)*4);           // offs
  s += alup((size_t)N*4);               // cursor
  s += alup((size_t)E*4);               // elist
  return s;
}

// ---------------- launch ----------------
extern "C" void kernel_launch(void* const* d_in, const int* in_sizes, int n_in,
                              void* d_out, int out_size, void* d_ws, size_t ws_size,
                              hipStream_t stream)
{
  const float* node_attrs = (const float*)d_in[0];
  const float* vectors    = (const float*)d_in[1];
  const float* we0        = (const float*)d_in[2];
  const float* we1        = (const float*)d_in[3];
  const float* winit      = (const float*)d_in[4];
  const float* wenv       = (const float*)d_in[5];
  const float* wlat0      = (const float*)d_in[6];
  const float* wlat1      = (const float*)d_in[7];
  const float* wmix       = (const float*)d_in[8];
  const float* wout       = (const float*)d_in[9];
  const int*   senders    = (const int*)d_in[10];
  const int*   receivers  = (const int*)d_in[11];
  float* out = (float*)d_out;
  const int E = in_sizes[1] / 3;
  const int N = in_sizes[0] / 16;

  int CHD = -1;
  const int tiers[4] = {E, E/2, E/4, CH};
  for (int i=0;i<4;i++){
    if (tiers[i] >= CH && need_bytes(E, N, tiers[i]) <= ws_size){ CHD = tiers[i]; break; }
  }
  if (CHD < 0) return;                  // diagnostic clean fail

  char* base = (char*)d_ws;
  size_t off = 0;
  auto carve = [&](size_t b) -> char* { char* p = base + off; off += alup(b); return p; };
  float*          Yb    = (float*)carve((size_t)E*16*4);
  float*          cutb  = (float*)carve((size_t)E*4);
  float*          nenv  = (float*)carve((size_t)N*512*4);
  unsigned short* feat  = (unsigned short*)carve((size_t)E*64*2);
  unsigned short* cbuf  = (unsigned short*)carve((size_t)CHD*512*2);
  unsigned short* Vb    = (unsigned short*)carve((size_t)E*512*2);
  unsigned short* xb    = (unsigned short*)carve((size_t)E*672*2);
  unsigned short* we0T  = (unsigned short*)carve((size_t)512*64*2);
  unsigned short* weF   = (unsigned short*)carve((size_t)768*512*2);
  unsigned short* winT  = (unsigned short*)carve((size_t)128*512*2);
  unsigned short* wenvT = (unsigned short*)carve((size_t)2*32*512*2);
  unsigned short* wl0T  = (unsigned short*)carve((size_t)2*512*576*2);
  unsigned short* wl1F  = (unsigned short*)carve((size_t)640*512*2);
  unsigned short* we1c  = (unsigned short*)carve((size_t)512*512*2);
  unsigned short* wl1c  = (unsigned short*)carve((size_t)512*512*2);
  float*          fv    = (float*)carve(512*4);
  int*            deg   = (int*)carve((size_t)N*4);
  int*            offs  = (int*)carve(((size_t)N+1)*4);
  int*            cursor= (int*)carve((size_t)N*4);
  int*            elist = (int*)carve((size_t)E*4);

  const float rs40  = 0.15811388300841897f;  // 1/sqrt(40)
  const float rs512 = 0.044194173824159216f; // 1/sqrt(512)
  const float rs544 = 0.042874646285627205f; // 1/sqrt(544)

  dim3 blk(256);
  // zero CSR scratch first (edge_init's fused histogram needs deg=0)
  hipMemsetAsync(deg, 0, (size_t)N*4, stream);
  hipMemsetAsync(cursor, 0, (size_t)N*4, stream);

  // batched weight conversion (one dispatch, 10 segments)
  WDesc wd;
  auto seg = [&](int i, const float* W, unsigned short* WT, int K, int Nn, int Kpad, int trans){
    int elems = trans ? Nn*Kpad : K*Nn;
    wd.s[i] = { W, WT, K, Nn, Kpad, (elems + 255)/256, trans };
  };
  seg(0, we0,   we0T, 40, 512, 64, 1);
  seg(1, we1,   weF,  512, 512, 512, 1);                                  // rows 0..512
  seg(2, winit, winT, 512, 128, 512, 1);
  seg(3, wenv,                  wenvT,                  512, 32, 512, 1);
  seg(4, wenv + (size_t)512*32, wenvT + (size_t)32*512, 512, 32, 512, 1);
  seg(5, wlat0,                   wl0T,                   544, 512, 576, 1);
  seg(6, wlat0 + (size_t)544*512, wl0T + (size_t)512*576, 544, 512, 576, 1);
  seg(7, wlat1,                   wl1F,  512, 512, 512, 1);               // rows 0..512
  seg(8, we1,   we1c, 512, 512, 512, 0);                                  // straight copy
  seg(9, wlat1, wl1c, 512, 512, 512, 0);
  int totblk = 0;
  for (int i=0;i<10;i++) totblk += wd.s[i].nblk;
  wconv_all<<<totblk, blk, 0, stream>>>(wd);
  wfuse_vec<<<2, blk, 0, stream>>>(wlat1 + (size_t)512*512, wout, fv);

  // weight-fusion GEMMs (write transposed, bf16):
  gemm_mfma<64,unsigned short,false,false,true><<<dim3(1,4), blk, 0, stream>>>(
      we1c, 512, 512, wenvT, 512, weF + (size_t)512*512, 512, nullptr, 32, 512, rs512*0.25f);
  gemm_mfma<128,unsigned short,false,false,true><<<dim3(1,4), blk, 0, stream>>>(
      we1c, 512, 512, winT, 512, weF + (size_t)544*512, 512, nullptr, 128, 512, rs512);
  gemm_mfma<64,unsigned short,false,false,true><<<dim3(1,4), blk, 0, stream>>>(
      wl1c, 512, 512, wenvT + (size_t)32*512, 512, wl1F + (size_t)512*512, 512, nullptr, 32, 512, rs512*0.25f);

  edge_init<<<E/256, blk, 0, stream>>>(vectors, node_attrs, senders, receivers, feat, Yb, cutb, deg, E);

  // CSR of receivers (histogram fused into edge_init)
  scan_k<<<1, blk, 0, stream>>>(deg, offs, N);
  fill_k<<<(E+255)/256, blk, 0, stream>>>(receivers, cursor, offs, elist, E);

  // edge embedding: feat -> h (silu) -> [x | w0 | wi] (cut) ; V init
  for (int c0 = 0; c0 < E; c0 += CHD) {
    gemm_mfma<128,unsigned short,true,false><<<dim3(4, CHD/128), blk, 0, stream>>>(
        feat + (size_t)c0*64, 64, 64, we0T, 64, cbuf, 512, nullptr, 512, 64, rs40);
    gemm_mfma<128,unsigned short,false,true><<<dim3(6, CHD/128), blk, 0, stream>>>(
        cbuf, 512, 512, weF, 512, xb + (size_t)c0*672, 672, cutb + c0, 672, 512, rs512);
    vbuild<<<(CHD*32)/256, blk, 0, stream>>>(xb + (size_t)c0*672, Yb + (size_t)c0*16, Vb + (size_t)c0*512, CHD);
  }

  for (int layer = 0; layer < 2; ++layer) {
    env_build<<<N, 512, 0, stream>>>(xb, Yb, elist, offs, nenv);
    if (layer == 0)
      tp_mix<<<E/8, blk, 0, stream>>>(nenv, senders, Vb,
          wmix, xb, E);
    else
      tp_last<<<(E*32)/256, blk, 0, stream>>>(nenv, senders, Vb, xb, E);
    for (int c0 = 0; c0 < E; c0 += CHD) {
      // lat0: pure K=576 GEMM over [x | t0 | (dead wi, zero-weighted)]
      gemm_mfma<128,unsigned short,true,false><<<dim3(4, CHD/128), blk, 0, stream>>>(
          xb + (size_t)c0*672, 672, 576, wl0T + (size_t)layer*512*576, 576,
          cbuf, 512, nullptr, 512, 576, rs544);
      if (layer == 0)
        // lat1 + fused wenv of next layer
        gemm_mfma<128,unsigned short,false,true><<<dim3(5, CHD/128), blk, 0, stream>>>(
            cbuf, 512, 512, wl1F, 512, xb + (size_t)c0*672, 672, cutb + c0, 544, 512, rs512);
      else
        // final lat1 GEMM eliminated: out = rs512^2 * cut * <h, wlat1@wout>
        out_fused<<<CHD/4, blk, 0, stream>>>(cbuf, fv, cutb + c0, out + c0, CHD);
    }
  }
}

// Round 17
// 601.069 us; speedup vs baseline: 1.1920x; 1.0509x over previous
//
#include <hip/hip_runtime.h>
#include <math.h>
#include <type_traits>

typedef __attribute__((ext_vector_type(8))) short s8v;   // 8 bf16 (4 VGPR)
typedef __attribute__((ext_vector_type(4))) float f4v;   // MFMA acc
typedef __attribute__((ext_vector_type(2))) float f2v;   // packed f32 pair

#define CH 8192

// ---------------- bf16 bit helpers ----------------
__device__ inline float b2f(unsigned short u){ return __uint_as_float(((unsigned)u)<<16); }
__device__ inline unsigned short f2b(float f){
  unsigned u = __float_as_uint(f);
  return (unsigned short)((u + 0x7FFFu + ((u>>16)&1u)) >> 16);   // RNE
}
__device__ inline void stC(float* p, float v){ *p = v; }
__device__ inline void stC(unsigned short* p, float v){ *p = f2b(v); }

// async global->LDS, 16B per lane; lds base must be wave-uniform
__device__ __forceinline__ void gl16(const void* g, void* l){
  __builtin_amdgcn_global_load_lds(
      (const __attribute__((address_space(1))) unsigned*)g,
      (__attribute__((address_space(3))) unsigned*)l, 16, 0, 0);
}

// ================= compile-time real Wigner (CG) tables =================
constexpr double FCT[11] = {1.,1.,2.,6.,24.,120.,720.,5040.,40320.,362880.,3628800.};
constexpr double csqrt_c(double x){
  double g = x > 1.0 ? x : 1.0;
  for (int i=0;i<60;i++) g = 0.5*(g + x/g);
  return g;
}
struct CD { double re, im; };
constexpr CD cmulc(CD a, CD b){ return {a.re*b.re - a.im*b.im, a.re*b.im + a.im*b.re}; }

constexpr double su2cg_c(int j1,int j2,int j3,int m1,int m2,int m3){
  if (m1+m2 != m3) return 0.0;
  double pref = csqrt_c((double)(2*j3+1) * FCT[j1+j2-j3]*FCT[j1-j2+j3]*FCT[-j1+j2+j3]/FCT[j1+j2+j3+1]
              * FCT[j3+m3]*FCT[j3-m3]*FCT[j1-m1]*FCT[j1+m1]*FCT[j2-m2]*FCT[j2+m2]);
  int kmin = 0;
  if (j2-j3-m1 > kmin) kmin = j2-j3-m1;
  if (j1-j3+m2 > kmin) kmin = j1-j3+m2;
  int kmax = j1+j2-j3;
  if (j1-m1 < kmax) kmax = j1-m1;
  if (j2+m2 < kmax) kmax = j2+m2;
  double s = 0.0;
  for (int k=kmin;k<=kmax;k++){
    double t = 1.0/(FCT[k]*FCT[j1+j2-j3-k]*FCT[j1-m1-k]*FCT[j2+m2-k]*FCT[j3-j2+m1+k]*FCT[j3-j1-m2+k]);
    s += (k&1) ? -t : t;
  }
  return pref*s;
}

constexpr CD qelem_c(int l, int i, int j){
  int m = i - l;
  const double is2 = 0.70710678118654752440;
  double re=0.0, im=0.0;
  if (m < 0){
    if (j == l - m) re = is2;
    else if (j == l + m) im = -is2;
  } else if (m == 0){
    if (j == l) re = 1.0;
  } else {
    double sgn = (m & 1) ? -1.0 : 1.0;
    if (j == l + m) re = sgn*is2;
    else if (j == l - m) im = sgn*is2;
  }
  CD r{};
  switch (l & 3){                    // (-i)^l
    case 0: r = {re, im}; break;
    case 1: r = {im, -re}; break;
    case 2: r = {-re, -im}; break;
    default: r = {-im, re}; break;
  }
  return r;
}

// path-count normalization per l3: n = {4,9,11,10}
constexpr double TN3[4] = {0.5, 1.0/3.0, 0.30151134457776363, 0.31622776601683794};

template<int L1,int L2,int L3>
struct TriVals { float v[(2*L1+1)*(2*L2+1)*(2*L3+1)]; };

template<int L1,int L2,int L3>
constexpr TriVals<L1,L2,L3> make_tri(){
  constexpr int n1=2*L1+1, n2=2*L2+1, n3=2*L3+1;
  double cg[n1*n2*n3] = {};
  for (int a=0;a<n1;a++)
    for (int b=0;b<n2;b++)
      for (int c=0;c<n3;c++)
        cg[(a*n2+b)*n3+c] = su2cg_c(L1,L2,L3, a-L1, b-L2, c-L3);
  double cr[n1*n2*n3] = {};
  double ci[n1*n2*n3] = {};
  for (int i=0;i<n1;i++)
   for (int j=0;j<n2;j++)
    for (int k=0;k<n3;k++){
      double sre=0.0, sim=0.0;
      for (int a=0;a<n1;a++){
        CD q1 = qelem_c(L1,i,a);
        if (q1.re==0.0 && q1.im==0.0) continue;
        for (int b=0;b<n2;b++){
          CD q2 = qelem_c(L2,j,b);
          if (q2.re==0.0 && q2.im==0.0) continue;
          CD q12 = cmulc(q1,q2);
          for (int c=0;c<n3;c++){
            double g = cg[(a*n2+b)*n3+c];
            if (g == 0.0) continue;
            CD q3 = qelem_c(L3,k,c);
            CD q3c{q3.re, -q3.im};
            CD q = cmulc(q12,q3c);
            sre += q.re*g; sim += q.im*g;
          }
        }
      }
      cr[(i*n2+j)*n3+k]=sre; ci[(i*n2+j)*n3+k]=sim;
    }
  double nr=0.0, ni=0.0;
  for (int i=0;i<n1*n2*n3;i++){ nr += cr[i]*cr[i]; ni += ci[i]*ci[i]; }
  bool pr = nr >= ni;
  double nn = csqrt_c(pr ? nr : ni);
  TriVals<L1,L2,L3> t{};
  for (int i=0;i<n1*n2*n3;i++)
    t.v[i] = (float)(((pr ? cr[i] : ci[i]) / nn) * TN3[L3]);
  return t;
}

template<int L1,int L2,int L3>
constexpr TriVals<L1,L2,L3> W3V = make_tri<L1,L2,L3>();

constexpr int LOFFC[4] = {0,1,4,9};

// ---- FMA with inline 32-bit literal (VOP2 v_fmac_f32, src0=literal: free) ----
template<int WB>
__device__ __forceinline__ void fmac_lit(float& a, float p){
  asm("v_fmac_f32 %0, %2, %1" : "+v"(a) : "v"(p), "i"(WB));
}

// static-for
template<int I, int N, typename F>
__device__ __forceinline__ void sfor(F&& f){
  if constexpr (I < N){
    f(std::integral_constant<int,I>{});
    sfor<I+1,N>(static_cast<F&&>(f));
  }
}

// grouped TP: one (L1,L2) pair -> each product computed ONCE, all valid l3 emitted
template<int L1,int L2>
__device__ __forceinline__ void tp_pair(const float* __restrict__ env,
                                        const float* __restrict__ v,
                                        float* __restrict__ acc){
  sfor<0,2*L1+1>([&](auto K1c){
    constexpr int k1 = decltype(K1c)::value;
    sfor<0,2*L2+1>([&](auto K2c){
      constexpr int k2 = decltype(K2c)::value;
      float p = env[LOFFC[L1]+k1] * v[LOFFC[L2]+k2];
      sfor<0,4>([&](auto L3c){
        constexpr int l3 = decltype(L3c)::value;
        constexpr int lo = (L1>L2)?(L1-L2):(L2-L1);
        if constexpr (l3 >= lo && l3 <= L1+L2){
          sfor<0,2*l3+1>([&](auto K3c){
            constexpr int k3 = decltype(K3c)::value;
            constexpr float w = W3V<L1,L2,l3>.v[(k1*(2*L2+1)+k2)*(2*l3+1)+k3];
            if constexpr (w != 0.f){
              fmac_lit<__builtin_bit_cast(int, w)>(acc[LOFFC[l3]+k3], p);
            }
          });
        }
      });
    });
  });
}

// scalar per-triple variant (tp_last, l3=0 only: tiny)
template<int L1,int L2,int L3>
__device__ __forceinline__ void tp_tri(const float* __restrict__ env,
                                       const float* __restrict__ v,
                                       float* __restrict__ acc){
  constexpr int n1=2*L1+1, n2=2*L2+1, n3=2*L3+1;
  #pragma unroll
  for (int k1=0;k1<n1;k1++)
    #pragma unroll
    for (int k2=0;k2<n2;k2++){
      float p = env[LOFFC[L1]+k1] * v[LOFFC[L2]+k2];
      #pragma unroll
      for (int k3=0;k3<n3;k3++){
        float w = W3V<L1,L2,L3>.v[(k1*n2+k2)*n3+k3];
        if (w != 0.f) acc[LOFFC[L3]+k3] += w * p;
      }
    }
}

// ---------------- batched weight convert (+optional transpose) ----------------
struct WSeg { const float* W; unsigned short* WT; int K, N, Kpad, nblk, trans; };
struct WDesc { WSeg s[10]; };
__global__ __launch_bounds__(256) void wconv_all(WDesc d){
  int b = blockIdx.x;
  int seg = 0;
  while (b >= d.s[seg].nblk){ b -= d.s[seg].nblk; ++seg; }
  const WSeg w = d.s[seg];
  int idx = b*256 + threadIdx.x;
  if (w.trans){
    if (idx >= w.N*w.Kpad) return;
    int n = idx / w.Kpad, k = idx - n*w.Kpad;
    w.WT[idx] = (k < w.K) ? f2b(w.W[(size_t)k*w.N + n]) : (unsigned short)0;
  } else {
    if (idx >= w.K*w.N) return;
    w.WT[idx] = f2b(w.W[idx]);
  }
}

// ---------------- fused output vector: fv = wlat1_l1 @ wout (fp32) -------------
__global__ __launch_bounds__(256) void wfuse_vec(
    const float* __restrict__ wl1_l1, const float* __restrict__ wout,
    float* __restrict__ fv)
{
  int k = blockIdx.x*256 + threadIdx.x;
  if (k >= 512) return;
  float s = 0.f;
  for (int n=0;n<512;n++) s += wl1_l1[(size_t)k*512 + n] * wout[n];
  fv[k] = s;
}

// ---------------- edge geometry + receiver histogram ----------------
__global__ __launch_bounds__(256) void edge_init(
    const float* __restrict__ vec, const float* __restrict__ na,
    const int* __restrict__ snd, const int* __restrict__ rcv,
    unsigned short* __restrict__ feat, float* __restrict__ Y, float* __restrict__ cutb,
    int* __restrict__ deg, int E)
{
  int e = blockIdx.x*256 + threadIdx.x;
  if (e >= E) return;
  float vx = vec[(size_t)e*3], vy = vec[(size_t)e*3+1], vz = vec[(size_t)e*3+2];
  float d = sqrtf(vx*vx + vy*vy + vz*vz);
  float inv = 1.f/(d + 1e-9f);
  float x = vx*inv, y = vy*inv, z = vz*inv;
  float dc = d * 0.4f;               // d / 2.5
  float dci = 1.f/(dc + 1e-9f);
  unsigned short* f = feat + (size_t)e*64;
  #pragma unroll
  for (int k=1;k<=8;k++)
    f[k-1] = f2b(1.41421356237309515f * sinf(dc * 3.14159265358979323846f * k) * dci);
  int s = snd[e], r = rcv[e];
  atomicAdd(&deg[r], 1);             // CSR histogram (fused; deg pre-zeroed)
  #pragma unroll
  for (int i=0;i<16;i++) f[8+i]  = f2b(na[(size_t)s*16+i]);
  #pragma unroll
  for (int i=0;i<16;i++) f[24+i] = f2b(na[(size_t)r*16+i]);
  #pragma unroll
  for (int i=40;i<64;i++) f[i] = 0;
  float cv = 0.f;
  if (dc < 1.f){
    float d2 = dc*dc; float d6 = d2*d2*d2; float d7 = d6*dc; float d8 = d7*dc;
    cv = 1.f - 28.f*d6 + 48.f*d7 - 21.f*d8;
  }
  cutb[e] = cv;
  float* Ye = Y + (size_t)e*16;
  const float s3=1.7320508075688772f, s5=2.2360679774997896f, s15=3.8729833462074170f;
  Ye[0] = 1.f;
  Ye[1] = s3*y; Ye[2] = s3*z; Ye[3] = s3*x;
  Ye[4] = s15*x*y; Ye[5] = s15*y*z; Ye[6] = 0.5f*s5*(3.f*z*z-1.f);
  Ye[7] = s15*x*z; Ye[8] = 0.5f*s15*(x*x - y*y);
  const float c1=2.0916500663351889f, c2=10.246950765959598f, c3=1.6201851746019649f, c4=1.3228756555322954f;
  Ye[9]  = c1*y*(3.f*x*x - y*y);
  Ye[10] = c2*x*y*z;
  Ye[11] = c3*y*(5.f*z*z - 1.f);
  Ye[12] = c4*z*(5.f*z*z - 3.f);
  Ye[13] = c3*x*(5.f*z*z - 1.f);
  Ye[14] = 0.5f*c2*z*(x*x - y*y);
  Ye[15] = c1*x*(x*x - 3.f*y*y);
}

// ---------------- MFMA bf16 GEMM with global_load_lds staging ------------------
// TSTORE: write C transposed (C[col*ldc+row]) — used for weight-fusion GEMMs.
// XCD-aware chunked swizzle (T1): consecutive linear block ids round-robin the
// 8 per-XCD L2s, so the NBcol col-blocks sharing one A row-panel land on
// DIFFERENT L2s -> A re-fetched ~NBcol x from HBM. Remap so each XCD owns a
// contiguous chunk (rows x all cols) -> panel col-blocks share one L2.
// Bijective iff nwg%8==0 (all big grids here: 2048/2560/3072); else identity.
template<int NT, typename TC, bool SILU, bool CUT, bool TSTORE=false>
__global__ __launch_bounds__(256) void gemm_mfma(
    const unsigned short* __restrict__ A, int lda, int K1,
    const unsigned short* __restrict__ WT, int ldw,
    TC* __restrict__ C, int ldc,
    const float* __restrict__ cutv,
    int N, int K, float scale)
{
  constexpr int NB = NT/16;
  __shared__ s8v As8[128*8];
  __shared__ s8v Bs8[NT*8];
  const int tid = threadIdx.x;
  const int wid = tid >> 6, lane = tid & 63;
  const int r15 = lane & 15, kg = lane >> 4;
  int bid = blockIdx.x + blockIdx.y * gridDim.x;
  const int nwg = gridDim.x * gridDim.y;
  if ((nwg & 7) == 0) bid = (bid & 7) * (nwg >> 3) + (bid >> 3);
  const int col0 = (bid % gridDim.x) * NT;
  const int row0 = (bid / gridDim.x) * 128;
  f4v acc[2][NB] = {};

  auto compute = [&](){
    #pragma unroll
    for (int s = 0; s < 2; s++) {
      const int cb = s*4 + kg;
      const int cx = cb ^ (r15 & 7);
      s8v a0 = As8[(wid*32      + r15)*8 + cx];
      s8v a1 = As8[(wid*32 + 16 + r15)*8 + cx];
      #pragma unroll
      for (int j = 0; j < NB; j++) {
        s8v b = Bs8[(j*16 + r15)*8 + cx];
        acc[0][j] = __builtin_amdgcn_mfma_f32_16x16x32_bf16(a0, b, acc[0][j], 0,0,0);
        acc[1][j] = __builtin_amdgcn_mfma_f32_16x16x32_bf16(a1, b, acc[1][j], 0,0,0);
      }
    }
  };

  for (int k0 = 0; k0 < K; k0 += 64) {
    #pragma unroll
    for (int i = 0; i < 4; i++) {       // A tile: 1024 segs of 16B
      int seg = i*256 + tid;
      int r = seg >> 3, ks = seg & 7;
      int ksx = ks ^ (r & 7);
      gl16(A + (size_t)(row0+r)*lda + k0 + ksx*8, &As8[i*256 + (tid & ~63)]);
    }
    #pragma unroll
    for (int i = 0; i < NT/32; i++) {   // B tile: NT*8 segs
      int seg = i*256 + tid;
      int n = seg >> 3, ks = seg & 7;
      int ksx = ks ^ (n & 7);
      gl16(WT + (size_t)(col0+n)*ldw + k0 + ksx*8, &Bs8[i*256 + (tid & ~63)]);
    }
    __syncthreads();
    compute();
    __syncthreads();
  }
  // epilogue: C/D layout col = lane&15, row = (lane>>4)*4 + j
  #pragma unroll
  for (int g=0; g<2; g++) {
    #pragma unroll
    for (int c=0; c<NB; c++) {
      int col = col0 + c*16 + r15;
      if (col >= N) continue;
      #pragma unroll
      for (int j=0;j<4;j++) {
        int row = row0 + wid*32 + g*16 + kg*4 + j;
        float v = acc[g][c][j] * scale;
        if (SILU) v = v / (1.f + __expf(-v));
        if (CUT)  v *= cutv[row];
        if (TSTORE) stC(&C[(size_t)col*ldc + row], v);
        else        stC(&C[(size_t)row*ldc + col], v);
      }
    }
  }
}

// ---------------- V init: thread per (e,m); wi = xb cols [544..672) ------------
__global__ __launch_bounds__(256) void vbuild(
    const unsigned short* __restrict__ xbc, const float* __restrict__ Y,
    unsigned short* __restrict__ V, int count)
{
  int t = blockIdx.x*256 + threadIdx.x;
  if (t >= count*32) return;
  int e = t >> 5, m = t & 31;
  const unsigned short* wr = xbc + (size_t)e*672 + 544 + m;
  float ws[4] = { b2f(wr[0]), b2f(wr[32]), b2f(wr[64]), b2f(wr[96]) };
  const float4* Y4 = (const float4*)(Y + (size_t)e*16);
  float yv[16];
  #pragma unroll
  for (int q=0;q<4;q++){ float4 f=Y4[q]; yv[q*4]=f.x; yv[q*4+1]=f.y; yv[q*4+2]=f.z; yv[q*4+3]=f.w; }
  constexpr int LOFK[16] = {0,1,1,1,2,2,2,2,2,3,3,3,3,3,3,3};
  s8v o0, o1;
  #pragma unroll
  for (int k=0;k<8;k++)  o0[k] = (short)f2b(ws[LOFK[k]]   * yv[k]);
  #pragma unroll
  for (int k=0;k<8;k++)  o1[k] = (short)f2b(ws[LOFK[8+k]] * yv[8+k]);
  s8v* vo = (s8v*)(V + (size_t)e*512 + (size_t)m*16);
  vo[0] = o0; vo[1] = o1;
}

// ---------------- CSR build: scan -> fill (histogram fused into edge_init) ----
__global__ __launch_bounds__(256) void scan_k(
    const int* __restrict__ deg, int* __restrict__ offs, int Nn)
{
  __shared__ int part[256];
  const int t = threadIdx.x;
  const int per = (Nn + 255) / 256;
  int base = t*per;
  int loc[32];
  int s = 0;
  for (int i=0;i<per;i++){ int v = (base+i<Nn)?deg[base+i]:0; loc[i]=s; s+=v; }
  part[t] = s;
  __syncthreads();
  for (int off=1; off<256; off<<=1){
    int v = (t>=off) ? part[t-off] : 0;
    __syncthreads();
    part[t] += v;
    __syncthreads();
  }
  int pre = (t==0) ? 0 : part[t-1];
  for (int i=0;i<per;i++) if (base+i<Nn) offs[base+i] = pre + loc[i];
  if (t==255) offs[Nn] = part[255];
}

__global__ __launch_bounds__(256) void fill_k(
    const int* __restrict__ rcv, int* __restrict__ cursor,
    const int* __restrict__ offs, int* __restrict__ elist, int E)
{
  int e = blockIdx.x*256 + threadIdx.x;
  if (e >= E) return;
  int r = rcv[e];
  int p = atomicAdd(&cursor[r], 1);
  elist[offs[r] + p] = e;
}

// ---------------- env build (w = bf16 cols [512..544) of xb) -------------------
__global__ __launch_bounds__(512) void env_build(
    const unsigned short* __restrict__ xb, const float* __restrict__ Y,
    const int* __restrict__ elist, const int* __restrict__ offs,
    float* __restrict__ nenv)
{
  const int n = blockIdx.x;
  const int j = threadIdx.x;          // 0..511
  const int m = j >> 4, kk = j & 15;
  const int beg = offs[n], end = offs[n+1];
  float acc = 0.f;
  for (int p = beg; p < end; ++p) {
    int e = elist[p];
    acc += b2f(xb[(size_t)e*672 + 512 + m]) * Y[(size_t)e*16 + kk];
  }
  nenv[(size_t)n*512 + j] = acc;
}

// ------------ fused tensor product + V-mix (layer 0; literal-fmac TP) ----------
// R14-measured codegen (VGPR 60, ~118us). Do NOT restructure: both the float4
// wm-table variant (R11) and the grid-stride persistent variant (R15) perturbed
// regalloc (32-VGPR spill / 128-VGPR bloat) and cost +45..+87us.
__global__ __launch_bounds__(256, 2) void tp_mix(
    const float* __restrict__ nenv, const int* __restrict__ senders,
    unsigned short* __restrict__ V,
    const float* __restrict__ wm,     // layer slice: [4][32][32]
    unsigned short* __restrict__ xb, int E)
{
  __shared__ float Ts[8][32][18];     // pitch 18: f2v-aligned rows, 2-way bank (free)
  const int tid = threadIdx.x;
  const int le = tid >> 5, m = tid & 31;
  const int e = blockIdx.x*8 + le;
  const int s = senders[e];
  float env[16], v[16], acc[16];
  const float4* ne4 = (const float4*)(nenv + (size_t)s*512 + (size_t)m*16);
  #pragma unroll
  for (int q=0;q<4;q++){
    float4 f = ne4[q];
    env[q*4]=f.x; env[q*4+1]=f.y; env[q*4+2]=f.z; env[q*4+3]=f.w;
  }
  const s8v* vv = (const s8v*)(V + (size_t)e*512 + (size_t)m*16);
  s8v v0 = vv[0], v1 = vv[1];
  #pragma unroll
  for (int q=0;q<8;q++){ v[q] = b2f((unsigned short)v0[q]); v[8+q] = b2f((unsigned short)v1[q]); }
  #pragma unroll
  for (int k=0;k<16;k++) acc[k] = 0.f;

  tp_pair<0,0>(env,v,acc); tp_pair<0,1>(env,v,acc); tp_pair<0,2>(env,v,acc); tp_pair<0,3>(env,v,acc);
  tp_pair<1,0>(env,v,acc); tp_pair<1,1>(env,v,acc); tp_pair<1,2>(env,v,acc); tp_pair<1,3>(env,v,acc);
  tp_pair<2,0>(env,v,acc); tp_pair<2,1>(env,v,acc); tp_pair<2,2>(env,v,acc); tp_pair<2,3>(env,v,acc);
  tp_pair<3,0>(env,v,acc); tp_pair<3,1>(env,v,acc); tp_pair<3,2>(env,v,acc); tp_pair<3,3>(env,v,acc);

  xb[(size_t)e*672 + 512 + m] = f2b(acc[0]);   // t0 (TN3 folded into W3V)

  #pragma unroll
  for (int k=0;k<16;k++) Ts[le][m][k] = acc[k];
  // (no barrier: same-wave producer/consumer)
  f2v o2[8];
  #pragma unroll
  for (int kp=0;kp<8;kp++){ o2[kp][0]=0.f; o2[kp][1]=0.f; }
  #pragma unroll
  for (int mm=0; mm<32; mm++) {
    float w0 = wm[        mm*32 + m];
    float w1 = wm[1024 +  mm*32 + m];
    float w2 = wm[2048 +  mm*32 + m];
    float w3 = wm[3072 +  mm*32 + m];
    const f2v* tr = (const f2v*)Ts[le][mm];
    f2v p01; p01[0]=w0; p01[1]=w1;
    f2v p11; p11[0]=w1; p11[1]=w1;
    f2v p22; p22[0]=w2; p22[1]=w2;
    f2v p23; p23[0]=w2; p23[1]=w3;
    f2v p33; p33[0]=w3; p33[1]=w3;
    o2[0] += tr[0]*p01; o2[1] += tr[1]*p11; o2[2] += tr[2]*p22; o2[3] += tr[3]*p22;
    o2[4] += tr[4]*p23; o2[5] += tr[5]*p33; o2[6] += tr[6]*p33; o2[7] += tr[7]*p33;
  }
  s8v oa, ob;
  #pragma unroll
  for (int kp=0;kp<4;kp++){
    oa[2*kp]   = (short)f2b(o2[kp][0]   * 0.17677669529663689f); // 1/sqrt(32)
    oa[2*kp+1] = (short)f2b(o2[kp][1]   * 0.17677669529663689f);
    ob[2*kp]   = (short)f2b(o2[4+kp][0] * 0.17677669529663689f);
    ob[2*kp+1] = (short)f2b(o2[4+kp][1] * 0.17677669529663689f);
  }
  s8v* vo = (s8v*)(V + (size_t)e*512 + (size_t)m*16);
  vo[0] = oa; vo[1] = ob;
}

// ------------ last-layer TP: only l3=0 survives; t0 -> xb bf16 ------------------
__global__ __launch_bounds__(256) void tp_last(
    const float* __restrict__ nenv, const int* __restrict__ senders,
    const unsigned short* __restrict__ V, unsigned short* __restrict__ xb, int E)
{
  int t = blockIdx.x*256 + threadIdx.x;
  int e = t >> 5, m = t & 31;
  if (e >= E) return;
  int s = senders[e];
  float env[16], v[16], acc[16];
  const float4* ne4 = (const float4*)(nenv + (size_t)s*512 + (size_t)m*16);
  #pragma unroll
  for (int q=0;q<4;q++){
    float4 f = ne4[q];
    env[q*4]=f.x; env[q*4+1]=f.y; env[q*4+2]=f.z; env[q*4+3]=f.w;
  }
  const s8v* vv = (const s8v*)(V + (size_t)e*512 + (size_t)m*16);
  s8v v0 = vv[0], v1 = vv[1];
  #pragma unroll
  for (int q=0;q<8;q++){ v[q] = b2f((unsigned short)v0[q]); v[8+q] = b2f((unsigned short)v1[q]); }
  #pragma unroll
  for (int k=0;k<16;k++) acc[k] = 0.f;
  tp_tri<0,0,0>(env,v,acc); tp_tri<1,1,0>(env,v,acc);
  tp_tri<2,2,0>(env,v,acc); tp_tri<3,3,0>(env,v,acc);
  xb[(size_t)e*672 + 512 + m] = f2b(acc[0]);
}

// -------- fused final output: out[e] = rs512^2 * cut[e] * dot(h[e], fv) --------
__global__ __launch_bounds__(256) void out_fused(
    const unsigned short* __restrict__ h, const float* __restrict__ fv,
    const float* __restrict__ cutv, float* __restrict__ out, int count)
{
  int gw = (blockIdx.x*256 + threadIdx.x) >> 6;
  int lane = threadIdx.x & 63;
  if (gw >= count) return;
  const s8v* xr = (const s8v*)(h + (size_t)gw*512);
  s8v chunk = xr[lane];
  float s = 0.f;
  #pragma unroll
  for (int j=0;j<8;j++) s += b2f((unsigned short)chunk[j]) * fv[lane*8 + j];
  #pragma unroll
  for (int off=32; off; off>>=1) s += __shfl_down(s, off);
  if (lane == 0)
    out[gw] = s * cutv[gw] * (0.044194173824159216f * 0.044194173824159216f);
}

// ---------------- workspace sizing ----------------
static inline size_t alup(size_t b){ return (b + 255) & ~(size_t)255; }
static size_t need_bytes(int E, int N, int chd){
  size_t s = 0;
  s += alup((size_t)E*16*4);            // Yb
  s += alup((size_t)E*4);               // cutb
  s += alup((size_t)N*512*4);           // nenv
  s += alup((size_t)E*64*2);            // feat
  s += alup((size_t)chd*512*2);         // cbuf
  s += alup((size_t)E*512*2);           // Vb
  s += alup((size_t)E*672*2);           // xb (x | w/t0 | wi)
  s += alup((size_t)512*64*2);          // we0T
  s += alup((size_t)768*512*2);         // weF (we1T + fused wenv0 + fused winit)
  s += alup((size_t)128*512*2);         // winT
  s += alup((size_t)2*32*512*2);        // wenvT
  s += alup((size_t)2*512*576*2);       // wl0T (Kpad 576)
  s += alup((size_t)640*512*2);         // wl1F (wlat1T_l0 + fused wenv1)
  s += alup((size_t)512*512*2);         // we1c
  s += alup((size_t)512*512*2);         // wl1c
  s += alup(512*4);                     // fv
  s += alup((size_t)N*4);               // deg
  s += alup(((size_t)N+1)*4);           // offs
  s += alup((size_t)N*4);               // cursor
  s += alup((size_t)E*4);               // elist
  return s;
}

// ---------------- launch ----------------
extern "C" void kernel_launch(void* const* d_in, const int* in_sizes, int n_in,
                              void* d_out, int out_size, void* d_ws, size_t ws_size,
                              hipStream_t stream)
{
  const float* node_attrs = (const float*)d_in[0];
  const float* vectors    = (const float*)d_in[1];
  const float* we0        = (const float*)d_in[2];
  const float* we1        = (const float*)d_in[3];
  const float* winit      = (const float*)d_in[4];
  const float* wenv       = (const float*)d_in[5];
  const float* wlat0      = (const float*)d_in[6];
  const float* wlat1      = (const float*)d_in[7];
  const float* wmix       = (const float*)d_in[8];
  const float* wout       = (const float*)d_in[9];
  const int*   senders    = (const int*)d_in[10];
  const int*   receivers  = (const int*)d_in[11];
  float* out = (float*)d_out;
  const int E = in_sizes[1] / 3;
  const int N = in_sizes[0] / 16;

  int CHD = -1;
  const int tiers[4] = {E, E/2, E/4, CH};
  for (int i=0;i<4;i++){
    if (tiers[i] >= CH && need_bytes(E, N, tiers[i]) <= ws_size){ CHD = tiers[i]; break; }
  }
  if (CHD < 0) return;                  // diagnostic clean fail

  char* base = (char*)d_ws;
  size_t off = 0;
  auto carve = [&](size_t b) -> char* { char* p = base + off; off += alup(b); return p; };
  float*          Yb    = (float*)carve((size_t)E*16*4);
  float*          cutb  = (float*)carve((size_t)E*4);
  float*          nenv  = (float*)carve((size_t)N*512*4);
  unsigned short* feat  = (unsigned short*)carve((size_t)E*64*2);
  unsigned short* cbuf  = (unsigned short*)carve((size_t)CHD*512*2);
  unsigned short* Vb    = (unsigned short*)carve((size_t)E*512*2);
  unsigned short* xb    = (unsigned short*)carve((size_t)E*672*2);
  unsigned short* we0T  = (unsigned short*)carve((size_t)512*64*2);
  unsigned short* weF   = (unsigned short*)carve((size_t)768*512*2);
  unsigned short* winT  = (unsigned short*)carve((size_t)128*512*2);
  unsigned short* wenvT = (unsigned short*)carve((size_t)2*32*512*2);
  unsigned short* wl0T  = (unsigned short*)carve((size_t)2*512*576*2);
  unsigned short* wl1F  = (unsigned short*)carve((size_t)640*512*2);
  unsigned short* we1c  = (unsigned short*)carve((size_t)512*512*2);
  unsigned short* wl1c  = (unsigned short*)carve((size_t)512*512*2);
  float*          fv    = (float*)carve(512*4);
  int*            deg   = (int*)carve((size_t)N*4);
  int*            offs  = (int*)carve(((size_t)N+1)*4);
  int*            cursor= (int*)carve((size_t)N*4);
  int*            elist = (int*)carve((size_t)E*4);

  const float rs40  = 0.15811388300841897f;  // 1/sqrt(40)
  const float rs512 = 0.044194173824159216f; // 1/sqrt(512)
  const float rs544 = 0.042874646285627205f; // 1/sqrt(544)

  dim3 blk(256);
  // zero CSR scratch first (edge_init's fused histogram needs deg=0)
  hipMemsetAsync(deg, 0, (size_t)N*4, stream);
  hipMemsetAsync(cursor, 0, (size_t)N*4, stream);

  // batched weight conversion (one dispatch, 10 segments)
  WDesc wd;
  auto seg = [&](int i, const float* W, unsigned short* WT, int K, int Nn, int Kpad, int trans){
    int elems = trans ? Nn*Kpad : K*Nn;
    wd.s[i] = { W, WT, K, Nn, Kpad, (elems + 255)/256, trans };
  };
  seg(0, we0,   we0T, 40, 512, 64, 1);
  seg(1, we1,   weF,  512, 512, 512, 1);                                  // rows 0..512
  seg(2, winit, winT, 512, 128, 512, 1);
  seg(3, wenv,                  wenvT,                  512, 32, 512, 1);
  seg(4, wenv + (size_t)512*32, wenvT + (size_t)32*512, 512, 32, 512, 1);
  seg(5, wlat0,                   wl0T,                   544, 512, 576, 1);
  seg(6, wlat0 + (size_t)544*512, wl0T + (size_t)512*576, 544, 512, 576, 1);
  seg(7, wlat1,                   wl1F,  512, 512, 512, 1);               // rows 0..512
  seg(8, we1,   we1c, 512, 512, 512, 0);                                  // straight copy
  seg(9, wlat1, wl1c, 512, 512, 512, 0);
  int totblk = 0;
  for (int i=0;i<10;i++) totblk += wd.s[i].nblk;
  wconv_all<<<totblk, blk, 0, stream>>>(wd);
  wfuse_vec<<<2, blk, 0, stream>>>(wlat1 + (size_t)512*512, wout, fv);

  // weight-fusion GEMMs (write transposed, bf16):
  gemm_mfma<64,unsigned short,false,false,true><<<dim3(1,4), blk, 0, stream>>>(
      we1c, 512, 512, wenvT, 512, weF + (size_t)512*512, 512, nullptr, 32, 512, rs512*0.25f);
  gemm_mfma<128,unsigned short,false,false,true><<<dim3(1,4), blk, 0, stream>>>(
      we1c, 512, 512, winT, 512, weF + (size_t)544*512, 512, nullptr, 128, 512, rs512);
  gemm_mfma<64,unsigned short,false,false,true><<<dim3(1,4), blk, 0, stream>>>(
      wl1c, 512, 512, wenvT + (size_t)32*512, 512, wl1F + (size_t)512*512, 512, nullptr, 32, 512, rs512*0.25f);

  edge_init<<<E/256, blk, 0, stream>>>(vectors, node_attrs, senders, receivers, feat, Yb, cutb, deg, E);

  // CSR of receivers (histogram fused into edge_init)
  scan_k<<<1, blk, 0, stream>>>(deg, offs, N);
  fill_k<<<(E+255)/256, blk, 0, stream>>>(receivers, cursor, offs, elist, E);

  // edge embedding: feat -> h (silu) -> [x | w0 | wi] (cut) ; V init
  for (int c0 = 0; c0 < E; c0 += CHD) {
    gemm_mfma<128,unsigned short,true,false><<<dim3(4, CHD/128), blk, 0, stream>>>(
        feat + (size_t)c0*64, 64, 64, we0T, 64, cbuf, 512, nullptr, 512, 64, rs40);
    gemm_mfma<128,unsigned short,false,true><<<dim3(6, CHD/128), blk, 0, stream>>>(
        cbuf, 512, 512, weF, 512, xb + (size_t)c0*672, 672, cutb + c0, 672, 512, rs512);
    vbuild<<<(CHD*32)/256, blk, 0, stream>>>(xb + (size_t)c0*672, Yb + (size_t)c0*16, Vb + (size_t)c0*512, CHD);
  }

  for (int layer = 0; layer < 2; ++layer) {
    env_build<<<N, 512, 0, stream>>>(xb, Yb, elist, offs, nenv);
    if (layer == 0)
      tp_mix<<<E/8, blk, 0, stream>>>(nenv, senders, Vb,
          wmix, xb, E);
    else
      tp_last<<<(E*32)/256, blk, 0, stream>>>(nenv, senders, Vb, xb, E);
    for (int c0 = 0; c0 < E; c0 += CHD) {
      // lat0: pure K=576 GEMM over [x | t0 | (dead wi, zero-weighted)]
      gemm_mfma<128,unsigned short,true,false><<<dim3(4, CHD/128), blk, 0, stream>>>(
          xb + (size_t)c0*672, 672, 576, wl0T + (size_t)layer*512*576, 576,
          cbuf, 512, nullptr, 512, 576, rs544);
      if (layer == 0)
        // lat1 + fused wenv of next layer
        gemm_mfma<128,unsigned short,false,true><<<dim3(5, CHD/128), blk, 0, stream>>>(
            cbuf, 512, 512, wl1F, 512, xb + (size_t)c0*672, 672, cutb + c0, 544, 512, rs512);
      else
        // final lat1 GEMM eliminated: out = rs512^2 * cut * <h, wlat1@wout>
        out_fused<<<CHD/4, blk, 0, stream>>>(cbuf, fv, cutb + c0, out + c0, CHD);
    }
  }
}

// Round 18
// 593.764 us; speedup vs baseline: 1.2066x; 1.0123x over previous
//
#include <hip/hip_runtime.h>
#include <math.h>
#include <type_traits>

typedef __attribute__((ext_vector_type(8))) short s8v;   // 8 bf16 (4 VGPR)
typedef __attribute__((ext_vector_type(4))) float f4v;   // MFMA acc
typedef __attribute__((ext_vector_type(2))) float f2v;   // packed f32 pair

#define CH 8192

// ---------------- bf16 bit helpers ----------------
__device__ inline float b2f(unsigned short u){ return __uint_as_float(((unsigned)u)<<16); }
__device__ inline unsigned short f2b(float f){
  unsigned u = __float_as_uint(f);
  return (unsigned short)((u + 0x7FFFu + ((u>>16)&1u)) >> 16);   // RNE
}
__device__ inline void stC(float* p, float v){ *p = v; }
__device__ inline void stC(unsigned short* p, float v){ *p = f2b(v); }

// async global->LDS, 16B per lane; lds base must be wave-uniform
__device__ __forceinline__ void gl16(const void* g, void* l){
  __builtin_amdgcn_global_load_lds(
      (const __attribute__((address_space(1))) unsigned*)g,
      (__attribute__((address_space(3))) unsigned*)l, 16, 0, 0);
}

// ================= compile-time real Wigner (CG) tables =================
constexpr double FCT[11] = {1.,1.,2.,6.,24.,120.,720.,5040.,40320.,362880.,3628800.};
constexpr double csqrt_c(double x){
  double g = x > 1.0 ? x : 1.0;
  for (int i=0;i<60;i++) g = 0.5*(g + x/g);
  return g;
}
struct CD { double re, im; };
constexpr CD cmulc(CD a, CD b){ return {a.re*b.re - a.im*b.im, a.re*b.im + a.im*b.re}; }

constexpr double su2cg_c(int j1,int j2,int j3,int m1,int m2,int m3){
  if (m1+m2 != m3) return 0.0;
  double pref = csqrt_c((double)(2*j3+1) * FCT[j1+j2-j3]*FCT[j1-j2+j3]*FCT[-j1+j2+j3]/FCT[j1+j2+j3+1]
              * FCT[j3+m3]*FCT[j3-m3]*FCT[j1-m1]*FCT[j1+m1]*FCT[j2-m2]*FCT[j2+m2]);
  int kmin = 0;
  if (j2-j3-m1 > kmin) kmin = j2-j3-m1;
  if (j1-j3+m2 > kmin) kmin = j1-j3+m2;
  int kmax = j1+j2-j3;
  if (j1-m1 < kmax) kmax = j1-m1;
  if (j2+m2 < kmax) kmax = j2+m2;
  double s = 0.0;
  for (int k=kmin;k<=kmax;k++){
    double t = 1.0/(FCT[k]*FCT[j1+j2-j3-k]*FCT[j1-m1-k]*FCT[j2+m2-k]*FCT[j3-j2+m1+k]*FCT[j3-j1-m2+k]);
    s += (k&1) ? -t : t;
  }
  return pref*s;
}

constexpr CD qelem_c(int l, int i, int j){
  int m = i - l;
  const double is2 = 0.70710678118654752440;
  double re=0.0, im=0.0;
  if (m < 0){
    if (j == l - m) re = is2;
    else if (j == l + m) im = -is2;
  } else if (m == 0){
    if (j == l) re = 1.0;
  } else {
    double sgn = (m & 1) ? -1.0 : 1.0;
    if (j == l + m) re = sgn*is2;
    else if (j == l - m) im = sgn*is2;
  }
  CD r{};
  switch (l & 3){                    // (-i)^l
    case 0: r = {re, im}; break;
    case 1: r = {im, -re}; break;
    case 2: r = {-re, -im}; break;
    default: r = {-im, re}; break;
  }
  return r;
}

// path-count normalization per l3: n = {4,9,11,10}
constexpr double TN3[4] = {0.5, 1.0/3.0, 0.30151134457776363, 0.31622776601683794};

template<int L1,int L2,int L3>
struct TriVals { float v[(2*L1+1)*(2*L2+1)*(2*L3+1)]; };

template<int L1,int L2,int L3>
constexpr TriVals<L1,L2,L3> make_tri(){
  constexpr int n1=2*L1+1, n2=2*L2+1, n3=2*L3+1;
  double cg[n1*n2*n3] = {};
  for (int a=0;a<n1;a++)
    for (int b=0;b<n2;b++)
      for (int c=0;c<n3;c++)
        cg[(a*n2+b)*n3+c] = su2cg_c(L1,L2,L3, a-L1, b-L2, c-L3);
  double cr[n1*n2*n3] = {};
  double ci[n1*n2*n3] = {};
  for (int i=0;i<n1;i++)
   for (int j=0;j<n2;j++)
    for (int k=0;k<n3;k++){
      double sre=0.0, sim=0.0;
      for (int a=0;a<n1;a++){
        CD q1 = qelem_c(L1,i,a);
        if (q1.re==0.0 && q1.im==0.0) continue;
        for (int b=0;b<n2;b++){
          CD q2 = qelem_c(L2,j,b);
          if (q2.re==0.0 && q2.im==0.0) continue;
          CD q12 = cmulc(q1,q2);
          for (int c=0;c<n3;c++){
            double g = cg[(a*n2+b)*n3+c];
            if (g == 0.0) continue;
            CD q3 = qelem_c(L3,k,c);
            CD q3c{q3.re, -q3.im};
            CD q = cmulc(q12,q3c);
            sre += q.re*g; sim += q.im*g;
          }
        }
      }
      cr[(i*n2+j)*n3+k]=sre; ci[(i*n2+j)*n3+k]=sim;
    }
  double nr=0.0, ni=0.0;
  for (int i=0;i<n1*n2*n3;i++){ nr += cr[i]*cr[i]; ni += ci[i]*ci[i]; }
  bool pr = nr >= ni;
  double nn = csqrt_c(pr ? nr : ni);
  TriVals<L1,L2,L3> t{};
  for (int i=0;i<n1*n2*n3;i++)
    t.v[i] = (float)(((pr ? cr[i] : ci[i]) / nn) * TN3[L3]);
  return t;
}

template<int L1,int L2,int L3>
constexpr TriVals<L1,L2,L3> W3V = make_tri<L1,L2,L3>();

constexpr int LOFFC[4] = {0,1,4,9};

// ---- FMA with inline 32-bit literal (VOP2 v_fmac_f32, src0=literal: free) ----
template<int WB>
__device__ __forceinline__ void fmac_lit(float& a, float p){
  asm("v_fmac_f32 %0, %2, %1" : "+v"(a) : "v"(p), "i"(WB));
}

// static-for
template<int I, int N, typename F>
__device__ __forceinline__ void sfor(F&& f){
  if constexpr (I < N){
    f(std::integral_constant<int,I>{});
    sfor<I+1,N>(static_cast<F&&>(f));
  }
}

// grouped TP: one (L1,L2) pair -> each product computed ONCE, all valid l3 emitted
template<int L1,int L2>
__device__ __forceinline__ void tp_pair(const float* __restrict__ env,
                                        const float* __restrict__ v,
                                        float* __restrict__ acc){
  sfor<0,2*L1+1>([&](auto K1c){
    constexpr int k1 = decltype(K1c)::value;
    sfor<0,2*L2+1>([&](auto K2c){
      constexpr int k2 = decltype(K2c)::value;
      float p = env[LOFFC[L1]+k1] * v[LOFFC[L2]+k2];
      sfor<0,4>([&](auto L3c){
        constexpr int l3 = decltype(L3c)::value;
        constexpr int lo = (L1>L2)?(L1-L2):(L2-L1);
        if constexpr (l3 >= lo && l3 <= L1+L2){
          sfor<0,2*l3+1>([&](auto K3c){
            constexpr int k3 = decltype(K3c)::value;
            constexpr float w = W3V<L1,L2,l3>.v[(k1*(2*L2+1)+k2)*(2*l3+1)+k3];
            if constexpr (w != 0.f){
              fmac_lit<__builtin_bit_cast(int, w)>(acc[LOFFC[l3]+k3], p);
            }
          });
        }
      });
    });
  });
}

// scalar per-triple variant (tp_last, l3=0 only: tiny)
template<int L1,int L2,int L3>
__device__ __forceinline__ void tp_tri(const float* __restrict__ env,
                                       const float* __restrict__ v,
                                       float* __restrict__ acc){
  constexpr int n1=2*L1+1, n2=2*L2+1, n3=2*L3+1;
  #pragma unroll
  for (int k1=0;k1<n1;k1++)
    #pragma unroll
    for (int k2=0;k2<n2;k2++){
      float p = env[LOFFC[L1]+k1] * v[LOFFC[L2]+k2];
      #pragma unroll
      for (int k3=0;k3<n3;k3++){
        float w = W3V<L1,L2,L3>.v[(k1*n2+k2)*n3+k3];
        if (w != 0.f) acc[LOFFC[L3]+k3] += w * p;
      }
    }
}

// ---------------- batched weight convert (+optional transpose) ----------------
struct WSeg { const float* W; unsigned short* WT; int K, N, Kpad, nblk, trans; };
struct WDesc { WSeg s[10]; };
__global__ __launch_bounds__(256) void wconv_all(WDesc d){
  int b = blockIdx.x;
  int seg = 0;
  while (b >= d.s[seg].nblk){ b -= d.s[seg].nblk; ++seg; }
  const WSeg w = d.s[seg];
  int idx = b*256 + threadIdx.x;
  if (w.trans){
    if (idx >= w.N*w.Kpad) return;
    int n = idx / w.Kpad, k = idx - n*w.Kpad;
    w.WT[idx] = (k < w.K) ? f2b(w.W[(size_t)k*w.N + n]) : (unsigned short)0;
  } else {
    if (idx >= w.K*w.N) return;
    w.WT[idx] = f2b(w.W[idx]);
  }
}

// ---------------- fused output vector: fv = wlat1_l1 @ wout (fp32) -------------
__global__ __launch_bounds__(256) void wfuse_vec(
    const float* __restrict__ wl1_l1, const float* __restrict__ wout,
    float* __restrict__ fv)
{
  int k = blockIdx.x*256 + threadIdx.x;
  if (k >= 512) return;
  float s = 0.f;
  for (int n=0;n<512;n++) s += wl1_l1[(size_t)k*512 + n] * wout[n];
  fv[k] = s;
}

// ---------------- edge geometry + receiver histogram ----------------
__global__ __launch_bounds__(256) void edge_init(
    const float* __restrict__ vec, const float* __restrict__ na,
    const int* __restrict__ snd, const int* __restrict__ rcv,
    unsigned short* __restrict__ feat, float* __restrict__ Y, float* __restrict__ cutb,
    int* __restrict__ deg, int E)
{
  int e = blockIdx.x*256 + threadIdx.x;
  if (e >= E) return;
  float vx = vec[(size_t)e*3], vy = vec[(size_t)e*3+1], vz = vec[(size_t)e*3+2];
  float d = sqrtf(vx*vx + vy*vy + vz*vz);
  float inv = 1.f/(d + 1e-9f);
  float x = vx*inv, y = vy*inv, z = vz*inv;
  float dc = d * 0.4f;               // d / 2.5
  float dci = 1.f/(dc + 1e-9f);
  unsigned short* f = feat + (size_t)e*64;
  #pragma unroll
  for (int k=1;k<=8;k++)
    f[k-1] = f2b(1.41421356237309515f * sinf(dc * 3.14159265358979323846f * k) * dci);
  int s = snd[e], r = rcv[e];
  atomicAdd(&deg[r], 1);             // CSR histogram (fused; deg pre-zeroed)
  #pragma unroll
  for (int i=0;i<16;i++) f[8+i]  = f2b(na[(size_t)s*16+i]);
  #pragma unroll
  for (int i=0;i<16;i++) f[24+i] = f2b(na[(size_t)r*16+i]);
  #pragma unroll
  for (int i=40;i<64;i++) f[i] = 0;
  float cv = 0.f;
  if (dc < 1.f){
    float d2 = dc*dc; float d6 = d2*d2*d2; float d7 = d6*dc; float d8 = d7*dc;
    cv = 1.f - 28.f*d6 + 48.f*d7 - 21.f*d8;
  }
  cutb[e] = cv;
  float* Ye = Y + (size_t)e*16;
  const float s3=1.7320508075688772f, s5=2.2360679774997896f, s15=3.8729833462074170f;
  Ye[0] = 1.f;
  Ye[1] = s3*y; Ye[2] = s3*z; Ye[3] = s3*x;
  Ye[4] = s15*x*y; Ye[5] = s15*y*z; Ye[6] = 0.5f*s5*(3.f*z*z-1.f);
  Ye[7] = s15*x*z; Ye[8] = 0.5f*s15*(x*x - y*y);
  const float c1=2.0916500663351889f, c2=10.246950765959598f, c3=1.6201851746019649f, c4=1.3228756555322954f;
  Ye[9]  = c1*y*(3.f*x*x - y*y);
  Ye[10] = c2*x*y*z;
  Ye[11] = c3*y*(5.f*z*z - 1.f);
  Ye[12] = c4*z*(5.f*z*z - 3.f);
  Ye[13] = c3*x*(5.f*z*z - 1.f);
  Ye[14] = 0.5f*c2*z*(x*x - y*y);
  Ye[15] = c1*x*(x*x - 3.f*y*y);
}

// ---------------- MFMA bf16 GEMM with global_load_lds staging ------------------
// TSTORE: write C transposed (C[col*ldc+row]) — used for weight-fusion GEMMs.
// XCD-aware chunked swizzle (T1), bijective iff nwg%8==0 (all big grids here).
template<int NT, typename TC, bool SILU, bool CUT, bool TSTORE=false>
__global__ __launch_bounds__(256) void gemm_mfma(
    const unsigned short* __restrict__ A, int lda, int K1,
    const unsigned short* __restrict__ WT, int ldw,
    TC* __restrict__ C, int ldc,
    const float* __restrict__ cutv,
    int N, int K, float scale)
{
  constexpr int NB = NT/16;
  __shared__ s8v As8[128*8];
  __shared__ s8v Bs8[NT*8];
  const int tid = threadIdx.x;
  const int wid = tid >> 6, lane = tid & 63;
  const int r15 = lane & 15, kg = lane >> 4;
  int bid = blockIdx.x + blockIdx.y * gridDim.x;
  const int nwg = gridDim.x * gridDim.y;
  if ((nwg & 7) == 0) bid = (bid & 7) * (nwg >> 3) + (bid >> 3);
  const int col0 = (bid % gridDim.x) * NT;
  const int row0 = (bid / gridDim.x) * 128;
  f4v acc[2][NB] = {};

  auto compute = [&](){
    #pragma unroll
    for (int s = 0; s < 2; s++) {
      const int cb = s*4 + kg;
      const int cx = cb ^ (r15 & 7);
      s8v a0 = As8[(wid*32      + r15)*8 + cx];
      s8v a1 = As8[(wid*32 + 16 + r15)*8 + cx];
      #pragma unroll
      for (int j = 0; j < NB; j++) {
        s8v b = Bs8[(j*16 + r15)*8 + cx];
        acc[0][j] = __builtin_amdgcn_mfma_f32_16x16x32_bf16(a0, b, acc[0][j], 0,0,0);
        acc[1][j] = __builtin_amdgcn_mfma_f32_16x16x32_bf16(a1, b, acc[1][j], 0,0,0);
      }
    }
  };

  for (int k0 = 0; k0 < K; k0 += 64) {
    #pragma unroll
    for (int i = 0; i < 4; i++) {       // A tile: 1024 segs of 16B
      int seg = i*256 + tid;
      int r = seg >> 3, ks = seg & 7;
      int ksx = ks ^ (r & 7);
      gl16(A + (size_t)(row0+r)*lda + k0 + ksx*8, &As8[i*256 + (tid & ~63)]);
    }
    #pragma unroll
    for (int i = 0; i < NT/32; i++) {   // B tile: NT*8 segs
      int seg = i*256 + tid;
      int n = seg >> 3, ks = seg & 7;
      int ksx = ks ^ (n & 7);
      gl16(WT + (size_t)(col0+n)*ldw + k0 + ksx*8, &Bs8[i*256 + (tid & ~63)]);
    }
    __syncthreads();
    compute();
    __syncthreads();
  }
  // epilogue: C/D layout col = lane&15, row = (lane>>4)*4 + j
  #pragma unroll
  for (int g=0; g<2; g++) {
    #pragma unroll
    for (int c=0; c<NB; c++) {
      int col = col0 + c*16 + r15;
      if (col >= N) continue;
      #pragma unroll
      for (int j=0;j<4;j++) {
        int row = row0 + wid*32 + g*16 + kg*4 + j;
        float v = acc[g][c][j] * scale;
        if (SILU) v = v / (1.f + __expf(-v));
        if (CUT)  v *= cutv[row];
        if (TSTORE) stC(&C[(size_t)col*ldc + row], v);
        else        stC(&C[(size_t)row*ldc + col], v);
      }
    }
  }
}

// ---------------- V init: thread per (e,m); wi = xb cols [544..672) ------------
__global__ __launch_bounds__(256) void vbuild(
    const unsigned short* __restrict__ xbc, const float* __restrict__ Y,
    unsigned short* __restrict__ V, int count)
{
  int t = blockIdx.x*256 + threadIdx.x;
  if (t >= count*32) return;
  int e = t >> 5, m = t & 31;
  const unsigned short* wr = xbc + (size_t)e*672 + 544 + m;
  float ws[4] = { b2f(wr[0]), b2f(wr[32]), b2f(wr[64]), b2f(wr[96]) };
  const float4* Y4 = (const float4*)(Y + (size_t)e*16);
  float yv[16];
  #pragma unroll
  for (int q=0;q<4;q++){ float4 f=Y4[q]; yv[q*4]=f.x; yv[q*4+1]=f.y; yv[q*4+2]=f.z; yv[q*4+3]=f.w; }
  constexpr int LOFK[16] = {0,1,1,1,2,2,2,2,2,3,3,3,3,3,3,3};
  s8v o0, o1;
  #pragma unroll
  for (int k=0;k<8;k++)  o0[k] = (short)f2b(ws[LOFK[k]]   * yv[k]);
  #pragma unroll
  for (int k=0;k<8;k++)  o1[k] = (short)f2b(ws[LOFK[8+k]] * yv[8+k]);
  s8v* vo = (s8v*)(V + (size_t)e*512 + (size_t)m*16);
  vo[0] = o0; vo[1] = o1;
}

// ---------------- CSR build: scan -> fill (histogram fused into edge_init) ----
__global__ __launch_bounds__(256) void scan_k(
    const int* __restrict__ deg, int* __restrict__ offs, int Nn)
{
  __shared__ int part[256];
  const int t = threadIdx.x;
  const int per = (Nn + 255) / 256;
  int base = t*per;
  int loc[32];
  int s = 0;
  for (int i=0;i<per;i++){ int v = (base+i<Nn)?deg[base+i]:0; loc[i]=s; s+=v; }
  part[t] = s;
  __syncthreads();
  for (int off=1; off<256; off<<=1){
    int v = (t>=off) ? part[t-off] : 0;
    __syncthreads();
    part[t] += v;
    __syncthreads();
  }
  int pre = (t==0) ? 0 : part[t-1];
  for (int i=0;i<per;i++) if (base+i<Nn) offs[base+i] = pre + loc[i];
  if (t==255) offs[Nn] = part[255];
}

__global__ __launch_bounds__(256) void fill_k(
    const int* __restrict__ rcv, int* __restrict__ cursor,
    const int* __restrict__ offs, int* __restrict__ elist, int E)
{
  int e = blockIdx.x*256 + threadIdx.x;
  if (e >= E) return;
  int r = rcv[e];
  int p = atomicAdd(&cursor[r], 1);
  elist[offs[r] + p] = e;
}

// ---------------- env build (w = bf16 cols [512..544) of xb) -------------------
__global__ __launch_bounds__(512) void env_build(
    const unsigned short* __restrict__ xb, const float* __restrict__ Y,
    const int* __restrict__ elist, const int* __restrict__ offs,
    float* __restrict__ nenv)
{
  const int n = blockIdx.x;
  const int j = threadIdx.x;          // 0..511
  const int m = j >> 4, kk = j & 15;
  const int beg = offs[n], end = offs[n+1];
  float acc = 0.f;
  for (int p = beg; p < end; ++p) {
    int e = elist[p];
    acc += b2f(xb[(size_t)e*672 + 512 + m]) * Y[(size_t)e*16 + kk];
  }
  nenv[(size_t)n*512 + j] = acc;
}

// ------------ fused tensor product + V-mix (layer 0; literal-fmac TP) ----------
// R14-measured body; ONLY change this round: Ts pitch 18 -> 16 (LDS 18432 ->
// 16384 B) to probe the effective-64KB-LDS-pool occupancy cap (3 -> 4 blocks/CU).
// Writes become bank-conflicted (one-time, ~2us); mix reads are broadcasts (free).
__global__ __launch_bounds__(256, 2) void tp_mix(
    const float* __restrict__ nenv, const int* __restrict__ senders,
    unsigned short* __restrict__ V,
    const float* __restrict__ wm,     // layer slice: [4][32][32]
    unsigned short* __restrict__ xb, int E)
{
  __shared__ float Ts[8][32][16];     // pitch 16: 16KB block -> 4 blocks @64KB pool
  const int tid = threadIdx.x;
  const int le = tid >> 5, m = tid & 31;
  const int e = blockIdx.x*8 + le;
  const int s = senders[e];
  float env[16], v[16], acc[16];
  const float4* ne4 = (const float4*)(nenv + (size_t)s*512 + (size_t)m*16);
  #pragma unroll
  for (int q=0;q<4;q++){
    float4 f = ne4[q];
    env[q*4]=f.x; env[q*4+1]=f.y; env[q*4+2]=f.z; env[q*4+3]=f.w;
  }
  const s8v* vv = (const s8v*)(V + (size_t)e*512 + (size_t)m*16);
  s8v v0 = vv[0], v1 = vv[1];
  #pragma unroll
  for (int q=0;q<8;q++){ v[q] = b2f((unsigned short)v0[q]); v[8+q] = b2f((unsigned short)v1[q]); }
  #pragma unroll
  for (int k=0;k<16;k++) acc[k] = 0.f;

  tp_pair<0,0>(env,v,acc); tp_pair<0,1>(env,v,acc); tp_pair<0,2>(env,v,acc); tp_pair<0,3>(env,v,acc);
  tp_pair<1,0>(env,v,acc); tp_pair<1,1>(env,v,acc); tp_pair<1,2>(env,v,acc); tp_pair<1,3>(env,v,acc);
  tp_pair<2,0>(env,v,acc); tp_pair<2,1>(env,v,acc); tp_pair<2,2>(env,v,acc); tp_pair<2,3>(env,v,acc);
  tp_pair<3,0>(env,v,acc); tp_pair<3,1>(env,v,acc); tp_pair<3,2>(env,v,acc); tp_pair<3,3>(env,v,acc);

  xb[(size_t)e*672 + 512 + m] = f2b(acc[0]);   // t0 (TN3 folded into W3V)

  #pragma unroll
  for (int k=0;k<16;k++) Ts[le][m][k] = acc[k];
  // (no barrier: same-wave producer/consumer)
  f2v o2[8];
  #pragma unroll
  for (int kp=0;kp<8;kp++){ o2[kp][0]=0.f; o2[kp][1]=0.f; }
  #pragma unroll
  for (int mm=0; mm<32; mm++) {
    float w0 = wm[        mm*32 + m];
    float w1 = wm[1024 +  mm*32 + m];
    float w2 = wm[2048 +  mm*32 + m];
    float w3 = wm[3072 +  mm*32 + m];
    const f2v* tr = (const f2v*)Ts[le][mm];
    f2v p01; p01[0]=w0; p01[1]=w1;
    f2v p11; p11[0]=w1; p11[1]=w1;
    f2v p22; p22[0]=w2; p22[1]=w2;
    f2v p23; p23[0]=w2; p23[1]=w3;
    f2v p33; p33[0]=w3; p33[1]=w3;
    o2[0] += tr[0]*p01; o2[1] += tr[1]*p11; o2[2] += tr[2]*p22; o2[3] += tr[3]*p22;
    o2[4] += tr[4]*p23; o2[5] += tr[5]*p33; o2[6] += tr[6]*p33; o2[7] += tr[7]*p33;
  }
  s8v oa, ob;
  #pragma unroll
  for (int kp=0;kp<4;kp++){
    oa[2*kp]   = (short)f2b(o2[kp][0]   * 0.17677669529663689f); // 1/sqrt(32)
    oa[2*kp+1] = (short)f2b(o2[kp][1]   * 0.17677669529663689f);
    ob[2*kp]   = (short)f2b(o2[4+kp][0] * 0.17677669529663689f);
    ob[2*kp+1] = (short)f2b(o2[4+kp][1] * 0.17677669529663689f);
  }
  s8v* vo = (s8v*)(V + (size_t)e*512 + (size_t)m*16);
  vo[0] = oa; vo[1] = ob;
}

// ------------ last-layer TP: only l3=0 survives; t0 -> xb bf16 ------------------
__global__ __launch_bounds__(256) void tp_last(
    const float* __restrict__ nenv, const int* __restrict__ senders,
    const unsigned short* __restrict__ V, unsigned short* __restrict__ xb, int E)
{
  int t = blockIdx.x*256 + threadIdx.x;
  int e = t >> 5, m = t & 31;
  if (e >= E) return;
  int s = senders[e];
  float env[16], v[16], acc[16];
  const float4* ne4 = (const float4*)(nenv + (size_t)s*512 + (size_t)m*16);
  #pragma unroll
  for (int q=0;q<4;q++){
    float4 f = ne4[q];
    env[q*4]=f.x; env[q*4+1]=f.y; env[q*4+2]=f.z; env[q*4+3]=f.w;
  }
  const s8v* vv = (const s8v*)(V + (size_t)e*512 + (size_t)m*16);
  s8v v0 = vv[0], v1 = vv[1];
  #pragma unroll
  for (int q=0;q<8;q++){ v[q] = b2f((unsigned short)v0[q]); v[8+q] = b2f((unsigned short)v1[q]); }
  #pragma unroll
  for (int k=0;k<16;k++) acc[k] = 0.f;
  tp_tri<0,0,0>(env,v,acc); tp_tri<1,1,0>(env,v,acc);
  tp_tri<2,2,0>(env,v,acc); tp_tri<3,3,0>(env,v,acc);
  xb[(size_t)e*672 + 512 + m] = f2b(acc[0]);
}

// -------- fused final output: out[e] = rs512^2 * cut[e] * dot(h[e], fv) --------
__global__ __launch_bounds__(256) void out_fused(
    const unsigned short* __restrict__ h, const float* __restrict__ fv,
    const float* __restrict__ cutv, float* __restrict__ out, int count)
{
  int gw = (blockIdx.x*256 + threadIdx.x) >> 6;
  int lane = threadIdx.x & 63;
  if (gw >= count) return;
  const s8v* xr = (const s8v*)(h + (size_t)gw*512);
  s8v chunk = xr[lane];
  float s = 0.f;
  #pragma unroll
  for (int j=0;j<8;j++) s += b2f((unsigned short)chunk[j]) * fv[lane*8 + j];
  #pragma unroll
  for (int off=32; off; off>>=1) s += __shfl_down(s, off);
  if (lane == 0)
    out[gw] = s * cutv[gw] * (0.044194173824159216f * 0.044194173824159216f);
}

// ---------------- workspace sizing ----------------
static inline size_t alup(size_t b){ return (b + 255) & ~(size_t)255; }
static size_t need_bytes(int E, int N, int chd){
  size_t s = 0;
  s += alup((size_t)E*16*4);            // Yb
  s += alup((size_t)E*4);               // cutb
  s += alup((size_t)N*512*4);           // nenv
  s += alup((size_t)E*64*2);            // feat
  s += alup((size_t)chd*512*2);         // cbuf
  s += alup((size_t)E*512*2);           // Vb
  s += alup((size_t)E*672*2);           // xb (x | w/t0 | wi)
  s += alup((size_t)512*64*2);          // we0T
  s += alup((size_t)768*512*2);         // weF (we1T + fused wenv0 + fused winit)
  s += alup((size_t)128*512*2);         // winT
  s += alup((size_t)2*32*512*2);        // wenvT
  s += alup((size_t)2*512*576*2);       // wl0T (Kpad 576)
  s += alup((size_t)640*512*2);         // wl1F (wlat1T_l0 + fused wenv1)
  s += alup((size_t)512*512*2);         // we1c
  s += alup((size_t)512*512*2);         // wl1c
  s += alup(512*4);                     // fv
  s += alup((size_t)N*4);               // deg
  s += alup(((size_t)N+1)*4);           // offs
  s += alup((size_t)N*4);               // cursor
  s += alup((size_t)E*4);               // elist
  return s;
}

// ---------------- launch ----------------
extern "C" void kernel_launch(void* const* d_in, const int* in_sizes, int n_in,
                              void* d_out, int out_size, void* d_ws, size_t ws_size,
                              hipStream_t stream)
{
  const float* node_attrs = (const float*)d_in[0];
  const float* vectors    = (const float*)d_in[1];
  const float* we0        = (const float*)d_in[2];
  const float* we1        = (const float*)d_in[3];
  const float* winit      = (const float*)d_in[4];
  const float* wenv       = (const float*)d_in[5];
  const float* wlat0      = (const float*)d_in[6];
  const float* wlat1      = (const float*)d_in[7];
  const float* wmix       = (const float*)d_in[8];
  const float* wout       = (const float*)d_in[9];
  const int*   senders    = (const int*)d_in[10];
  const int*   receivers  = (const int*)d_in[11];
  float* out = (float*)d_out;
  const int E = in_sizes[1] / 3;
  const int N = in_sizes[0] / 16;

  int CHD = -1;
  const int tiers[4] = {E, E/2, E/4, CH};
  for (int i=0;i<4;i++){
    if (tiers[i] >= CH && need_bytes(E, N, tiers[i]) <= ws_size){ CHD = tiers[i]; break; }
  }
  if (CHD < 0) return;                  // diagnostic clean fail

  char* base = (char*)d_ws;
  size_t off = 0;
  auto carve = [&](size_t b) -> char* { char* p = base + off; off += alup(b); return p; };
  float*          Yb    = (float*)carve((size_t)E*16*4);
  float*          cutb  = (float*)carve((size_t)E*4);
  float*          nenv  = (float*)carve((size_t)N*512*4);
  unsigned short* feat  = (unsigned short*)carve((size_t)E*64*2);
  unsigned short* cbuf  = (unsigned short*)carve((size_t)CHD*512*2);
  unsigned short* Vb    = (unsigned short*)carve((size_t)E*512*2);
  unsigned short* xb    = (unsigned short*)carve((size_t)E*672*2);
  unsigned short* we0T  = (unsigned short*)carve((size_t)512*64*2);
  unsigned short* weF   = (unsigned short*)carve((size_t)768*512*2);
  unsigned short* winT  = (unsigned short*)carve((size_t)128*512*2);
  unsigned short* wenvT = (unsigned short*)carve((size_t)2*32*512*2);
  unsigned short* wl0T  = (unsigned short*)carve((size_t)2*512*576*2);
  unsigned short* wl1F  = (unsigned short*)carve((size_t)640*512*2);
  unsigned short* we1c  = (unsigned short*)carve((size_t)512*512*2);
  unsigned short* wl1c  = (unsigned short*)carve((size_t)512*512*2);
  float*          fv    = (float*)carve(512*4);
  int*            deg   = (int*)carve((size_t)N*4);
  int*            offs  = (int*)carve(((size_t)N+1)*4);
  int*            cursor= (int*)carve((size_t)N*4);
  int*            elist = (int*)carve((size_t)E*4);

  const float rs40  = 0.15811388300841897f;  // 1/sqrt(40)
  const float rs512 = 0.044194173824159216f; // 1/sqrt(512)
  const float rs544 = 0.042874646285627205f; // 1/sqrt(544)

  dim3 blk(256);
  // zero CSR scratch first (edge_init's fused histogram needs deg=0)
  hipMemsetAsync(deg, 0, (size_t)N*4, stream);
  hipMemsetAsync(cursor, 0, (size_t)N*4, stream);

  // batched weight conversion (one dispatch, 10 segments)
  WDesc wd;
  auto seg = [&](int i, const float* W, unsigned short* WT, int K, int Nn, int Kpad, int trans){
    int elems = trans ? Nn*Kpad : K*Nn;
    wd.s[i] = { W, WT, K, Nn, Kpad, (elems + 255)/256, trans };
  };
  seg(0, we0,   we0T, 40, 512, 64, 1);
  seg(1, we1,   weF,  512, 512, 512, 1);                                  // rows 0..512
  seg(2, winit, winT, 512, 128, 512, 1);
  seg(3, wenv,                  wenvT,                  512, 32, 512, 1);
  seg(4, wenv + (size_t)512*32, wenvT + (size_t)32*512, 512, 32, 512, 1);
  seg(5, wlat0,                   wl0T,                   544, 512, 576, 1);
  seg(6, wlat0 + (size_t)544*512, wl0T + (size_t)512*576, 544, 512, 576, 1);
  seg(7, wlat1,                   wl1F,  512, 512, 512, 1);               // rows 0..512
  seg(8, we1,   we1c, 512, 512, 512, 0);                                  // straight copy
  seg(9, wlat1, wl1c, 512, 512, 512, 0);
  int totblk = 0;
  for (int i=0;i<10;i++) totblk += wd.s[i].nblk;
  wconv_all<<<totblk, blk, 0, stream>>>(wd);
  wfuse_vec<<<2, blk, 0, stream>>>(wlat1 + (size_t)512*512, wout, fv);

  // weight-fusion GEMMs (write transposed, bf16):
  gemm_mfma<64,unsigned short,false,false,true><<<dim3(1,4), blk, 0, stream>>>(
      we1c, 512, 512, wenvT, 512, weF + (size_t)512*512, 512, nullptr, 32, 512, rs512*0.25f);
  gemm_mfma<128,unsigned short,false,false,true><<<dim3(1,4), blk, 0, stream>>>(
      we1c, 512, 512, winT, 512, weF + (size_t)544*512, 512, nullptr, 128, 512, rs512);
  gemm_mfma<64,unsigned short,false,false,true><<<dim3(1,4), blk, 0, stream>>>(
      wl1c, 512, 512, wenvT + (size_t)32*512, 512, wl1F + (size_t)512*512, 512, nullptr, 32, 512, rs512*0.25f);

  edge_init<<<E/256, blk, 0, stream>>>(vectors, node_attrs, senders, receivers, feat, Yb, cutb, deg, E);

  // CSR of receivers (histogram fused into edge_init)
  scan_k<<<1, blk, 0, stream>>>(deg, offs, N);
  fill_k<<<(E+255)/256, blk, 0, stream>>>(receivers, cursor, offs, elist, E);

  // edge embedding: feat -> h (silu) -> [x | w0 | wi] (cut) ; V init
  for (int c0 = 0; c0 < E; c0 += CHD) {
    gemm_mfma<128,unsigned short,true,false><<<dim3(4, CHD/128), blk, 0, stream>>>(
        feat + (size_t)c0*64, 64, 64, we0T, 64, cbuf, 512, nullptr, 512, 64, rs40);
    gemm_mfma<128,unsigned short,false,true><<<dim3(6, CHD/128), blk, 0, stream>>>(
        cbuf, 512, 512, weF, 512, xb + (size_t)c0*672, 672, cutb + c0, 672, 512, rs512);
    vbuild<<<(CHD*32)/256, blk, 0, stream>>>(xb + (size_t)c0*672, Yb + (size_t)c0*16, Vb + (size_t)c0*512, CHD);
  }

  for (int layer = 0; layer < 2; ++layer) {
    env_build<<<N, 512, 0, stream>>>(xb, Yb, elist, offs, nenv);
    if (layer == 0)
      tp_mix<<<E/8, blk, 0, stream>>>(nenv, senders, Vb,
          wmix, xb, E);
    else
      tp_last<<<(E*32)/256, blk, 0, stream>>>(nenv, senders, Vb, xb, E);
    for (int c0 = 0; c0 < E; c0 += CHD) {
      // lat0: pure K=576 GEMM over [x | t0 | (dead wi, zero-weighted)]
      gemm_mfma<128,unsigned short,true,false><<<dim3(4, CHD/128), blk, 0, stream>>>(
          xb + (size_t)c0*672, 672, 576, wl0T + (size_t)layer*512*576, 576,
          cbuf, 512, nullptr, 512, 576, rs544);
      if (layer == 0)
        // lat1 + fused wenv of next layer
        gemm_mfma<128,unsigned short,false,true><<<dim3(5, CHD/128), blk, 0, stream>>>(
            cbuf, 512, 512, wl1F, 512, xb + (size_t)c0*672, 672, cutb + c0, 544, 512, rs512);
      else
        // final lat1 GEMM eliminated: out = rs512^2 * cut * <h, wlat1@wout>
        out_fused<<<CHD/4, blk, 0, stream>>>(cbuf, fv, cutb + c0, out + c0, CHD);
    }
  }
}

// Round 19
// 589.404 us; speedup vs baseline: 1.2155x; 1.0074x over previous
//
#include <hip/hip_runtime.h>
#include <math.h>
#include <type_traits>

typedef __attribute__((ext_vector_type(8))) short s8v;   // 8 bf16 (4 VGPR)
typedef __attribute__((ext_vector_type(4))) float f4v;   // MFMA acc
typedef __attribute__((ext_vector_type(2))) float f2v;   // packed f32 pair

#define CH 8192

// ---------------- bf16 bit helpers ----------------
__device__ inline float b2f(unsigned short u){ return __uint_as_float(((unsigned)u)<<16); }
__device__ inline unsigned short f2b(float f){
  unsigned u = __float_as_uint(f);
  return (unsigned short)((u + 0x7FFFu + ((u>>16)&1u)) >> 16);   // RNE
}
__device__ inline void stC(float* p, float v){ *p = v; }
__device__ inline void stC(unsigned short* p, float v){ *p = f2b(v); }

// async global->LDS, 16B per lane; lds base must be wave-uniform
__device__ __forceinline__ void gl16(const void* g, void* l){
  __builtin_amdgcn_global_load_lds(
      (const __attribute__((address_space(1))) unsigned*)g,
      (__attribute__((address_space(3))) unsigned*)l, 16, 0, 0);
}

// ================= compile-time real Wigner (CG) tables =================
constexpr double FCT[11] = {1.,1.,2.,6.,24.,120.,720.,5040.,40320.,362880.,3628800.};
constexpr double csqrt_c(double x){
  double g = x > 1.0 ? x : 1.0;
  for (int i=0;i<60;i++) g = 0.5*(g + x/g);
  return g;
}
struct CD { double re, im; };
constexpr CD cmulc(CD a, CD b){ return {a.re*b.re - a.im*b.im, a.re*b.im + a.im*b.re}; }

constexpr double su2cg_c(int j1,int j2,int j3,int m1,int m2,int m3){
  if (m1+m2 != m3) return 0.0;
  double pref = csqrt_c((double)(2*j3+1) * FCT[j1+j2-j3]*FCT[j1-j2+j3]*FCT[-j1+j2+j3]/FCT[j1+j2+j3+1]
              * FCT[j3+m3]*FCT[j3-m3]*FCT[j1-m1]*FCT[j1+m1]*FCT[j2-m2]*FCT[j2+m2]);
  int kmin = 0;
  if (j2-j3-m1 > kmin) kmin = j2-j3-m1;
  if (j1-j3+m2 > kmin) kmin = j1-j3+m2;
  int kmax = j1+j2-j3;
  if (j1-m1 < kmax) kmax = j1-m1;
  if (j2+m2 < kmax) kmax = j2+m2;
  double s = 0.0;
  for (int k=kmin;k<=kmax;k++){
    double t = 1.0/(FCT[k]*FCT[j1+j2-j3-k]*FCT[j1-m1-k]*FCT[j2+m2-k]*FCT[j3-j2+m1+k]*FCT[j3-j1-m2+k]);
    s += (k&1) ? -t : t;
  }
  return pref*s;
}

constexpr CD qelem_c(int l, int i, int j){
  int m = i - l;
  const double is2 = 0.70710678118654752440;
  double re=0.0, im=0.0;
  if (m < 0){
    if (j == l - m) re = is2;
    else if (j == l + m) im = -is2;
  } else if (m == 0){
    if (j == l) re = 1.0;
  } else {
    double sgn = (m & 1) ? -1.0 : 1.0;
    if (j == l + m) re = sgn*is2;
    else if (j == l - m) im = sgn*is2;
  }
  CD r{};
  switch (l & 3){                    // (-i)^l
    case 0: r = {re, im}; break;
    case 1: r = {im, -re}; break;
    case 2: r = {-re, -im}; break;
    default: r = {-im, re}; break;
  }
  return r;
}

// path-count normalization per l3: n = {4,9,11,10}
constexpr double TN3[4] = {0.5, 1.0/3.0, 0.30151134457776363, 0.31622776601683794};

template<int L1,int L2,int L3>
struct TriVals { float v[(2*L1+1)*(2*L2+1)*(2*L3+1)]; };

template<int L1,int L2,int L3>
constexpr TriVals<L1,L2,L3> make_tri(){
  constexpr int n1=2*L1+1, n2=2*L2+1, n3=2*L3+1;
  double cg[n1*n2*n3] = {};
  for (int a=0;a<n1;a++)
    for (int b=0;b<n2;b++)
      for (int c=0;c<n3;c++)
        cg[(a*n2+b)*n3+c] = su2cg_c(L1,L2,L3, a-L1, b-L2, c-L3);
  double cr[n1*n2*n3] = {};
  double ci[n1*n2*n3] = {};
  for (int i=0;i<n1;i++)
   for (int j=0;j<n2;j++)
    for (int k=0;k<n3;k++){
      double sre=0.0, sim=0.0;
      for (int a=0;a<n1;a++){
        CD q1 = qelem_c(L1,i,a);
        if (q1.re==0.0 && q1.im==0.0) continue;
        for (int b=0;b<n2;b++){
          CD q2 = qelem_c(L2,j,b);
          if (q2.re==0.0 && q2.im==0.0) continue;
          CD q12 = cmulc(q1,q2);
          for (int c=0;c<n3;c++){
            double g = cg[(a*n2+b)*n3+c];
            if (g == 0.0) continue;
            CD q3 = qelem_c(L3,k,c);
            CD q3c{q3.re, -q3.im};
            CD q = cmulc(q12,q3c);
            sre += q.re*g; sim += q.im*g;
          }
        }
      }
      cr[(i*n2+j)*n3+k]=sre; ci[(i*n2+j)*n3+k]=sim;
    }
  double nr=0.0, ni=0.0;
  for (int i=0;i<n1*n2*n3;i++){ nr += cr[i]*cr[i]; ni += ci[i]*ci[i]; }
  bool pr = nr >= ni;
  double nn = csqrt_c(pr ? nr : ni);
  TriVals<L1,L2,L3> t{};
  for (int i=0;i<n1*n2*n3;i++)
    t.v[i] = (float)(((pr ? cr[i] : ci[i]) / nn) * TN3[L3]);
  return t;
}

template<int L1,int L2,int L3>
constexpr TriVals<L1,L2,L3> W3V = make_tri<L1,L2,L3>();

constexpr int LOFFC[4] = {0,1,4,9};

// ---- FMA with inline 32-bit literal (VOP2 v_fmac_f32, src0=literal: free) ----
template<int WB>
__device__ __forceinline__ void fmac_lit(float& a, float p){
  asm("v_fmac_f32 %0, %2, %1" : "+v"(a) : "v"(p), "i"(WB));
}

// static-for
template<int I, int N, typename F>
__device__ __forceinline__ void sfor(F&& f){
  if constexpr (I < N){
    f(std::integral_constant<int,I>{});
    sfor<I+1,N>(static_cast<F&&>(f));
  }
}

// grouped TP: one (L1,L2) pair -> each product computed ONCE, all valid l3 emitted
template<int L1,int L2>
__device__ __forceinline__ void tp_pair(const float* __restrict__ env,
                                        const float* __restrict__ v,
                                        float* __restrict__ acc){
  sfor<0,2*L1+1>([&](auto K1c){
    constexpr int k1 = decltype(K1c)::value;
    sfor<0,2*L2+1>([&](auto K2c){
      constexpr int k2 = decltype(K2c)::value;
      float p = env[LOFFC[L1]+k1] * v[LOFFC[L2]+k2];
      sfor<0,4>([&](auto L3c){
        constexpr int l3 = decltype(L3c)::value;
        constexpr int lo = (L1>L2)?(L1-L2):(L2-L1);
        if constexpr (l3 >= lo && l3 <= L1+L2){
          sfor<0,2*l3+1>([&](auto K3c){
            constexpr int k3 = decltype(K3c)::value;
            constexpr float w = W3V<L1,L2,l3>.v[(k1*(2*L2+1)+k2)*(2*l3+1)+k3];
            if constexpr (w != 0.f){
              fmac_lit<__builtin_bit_cast(int, w)>(acc[LOFFC[l3]+k3], p);
            }
          });
        }
      });
    });
  });
}

// scalar per-triple variant (tp_last, l3=0 only: tiny)
template<int L1,int L2,int L3>
__device__ __forceinline__ void tp_tri(const float* __restrict__ env,
                                       const float* __restrict__ v,
                                       float* __restrict__ acc){
  constexpr int n1=2*L1+1, n2=2*L2+1, n3=2*L3+1;
  #pragma unroll
  for (int k1=0;k1<n1;k1++)
    #pragma unroll
    for (int k2=0;k2<n2;k2++){
      float p = env[LOFFC[L1]+k1] * v[LOFFC[L2]+k2];
      #pragma unroll
      for (int k3=0;k3<n3;k3++){
        float w = W3V<L1,L2,L3>.v[(k1*n2+k2)*n3+k3];
        if (w != 0.f) acc[LOFFC[L3]+k3] += w * p;
      }
    }
}

// ---------------- batched weight convert (+optional transpose) ----------------
struct WSeg { const float* W; unsigned short* WT; int K, N, Kpad, nblk, trans; };
struct WDesc { WSeg s[10]; };
__global__ __launch_bounds__(256) void wconv_all(WDesc d){
  int b = blockIdx.x;
  int seg = 0;
  while (b >= d.s[seg].nblk){ b -= d.s[seg].nblk; ++seg; }
  const WSeg w = d.s[seg];
  int idx = b*256 + threadIdx.x;
  if (w.trans){
    if (idx >= w.N*w.Kpad) return;
    int n = idx / w.Kpad, k = idx - n*w.Kpad;
    w.WT[idx] = (k < w.K) ? f2b(w.W[(size_t)k*w.N + n]) : (unsigned short)0;
  } else {
    if (idx >= w.K*w.N) return;
    w.WT[idx] = f2b(w.W[idx]);
  }
}

// ---------------- fused output vector: fv = wlat1_l1 @ wout (fp32) -------------
__global__ __launch_bounds__(256) void wfuse_vec(
    const float* __restrict__ wl1_l1, const float* __restrict__ wout,
    float* __restrict__ fv)
{
  int k = blockIdx.x*256 + threadIdx.x;
  if (k >= 512) return;
  float s = 0.f;
  for (int n=0;n<512;n++) s += wl1_l1[(size_t)k*512 + n] * wout[n];
  fv[k] = s;
}

// ---------------- edge geometry + receiver histogram ----------------
__global__ __launch_bounds__(256) void edge_init(
    const float* __restrict__ vec, const float* __restrict__ na,
    const int* __restrict__ snd, const int* __restrict__ rcv,
    unsigned short* __restrict__ feat, float* __restrict__ Y, float* __restrict__ cutb,
    int* __restrict__ deg, int E)
{
  int e = blockIdx.x*256 + threadIdx.x;
  if (e >= E) return;
  float vx = vec[(size_t)e*3], vy = vec[(size_t)e*3+1], vz = vec[(size_t)e*3+2];
  float d = sqrtf(vx*vx + vy*vy + vz*vz);
  float inv = 1.f/(d + 1e-9f);
  float x = vx*inv, y = vy*inv, z = vz*inv;
  float dc = d * 0.4f;               // d / 2.5
  float dci = 1.f/(dc + 1e-9f);
  unsigned short* f = feat + (size_t)e*64;
  #pragma unroll
  for (int k=1;k<=8;k++)
    f[k-1] = f2b(1.41421356237309515f * sinf(dc * 3.14159265358979323846f * k) * dci);
  int s = snd[e], r = rcv[e];
  atomicAdd(&deg[r], 1);             // CSR histogram (fused; deg pre-zeroed)
  #pragma unroll
  for (int i=0;i<16;i++) f[8+i]  = f2b(na[(size_t)s*16+i]);
  #pragma unroll
  for (int i=0;i<16;i++) f[24+i] = f2b(na[(size_t)r*16+i]);
  #pragma unroll
  for (int i=40;i<64;i++) f[i] = 0;
  float cv = 0.f;
  if (dc < 1.f){
    float d2 = dc*dc; float d6 = d2*d2*d2; float d7 = d6*dc; float d8 = d7*dc;
    cv = 1.f - 28.f*d6 + 48.f*d7 - 21.f*d8;
  }
  cutb[e] = cv;
  float* Ye = Y + (size_t)e*16;
  const float s3=1.7320508075688772f, s5=2.2360679774997896f, s15=3.8729833462074170f;
  Ye[0] = 1.f;
  Ye[1] = s3*y; Ye[2] = s3*z; Ye[3] = s3*x;
  Ye[4] = s15*x*y; Ye[5] = s15*y*z; Ye[6] = 0.5f*s5*(3.f*z*z-1.f);
  Ye[7] = s15*x*z; Ye[8] = 0.5f*s15*(x*x - y*y);
  const float c1=2.0916500663351889f, c2=10.246950765959598f, c3=1.6201851746019649f, c4=1.3228756555322954f;
  Ye[9]  = c1*y*(3.f*x*x - y*y);
  Ye[10] = c2*x*y*z;
  Ye[11] = c3*y*(5.f*z*z - 1.f);
  Ye[12] = c4*z*(5.f*z*z - 3.f);
  Ye[13] = c3*x*(5.f*z*z - 1.f);
  Ye[14] = 0.5f*c2*z*(x*x - y*y);
  Ye[15] = c1*x*(x*x - 3.f*y*y);
}

// ---------------- MFMA bf16 GEMM with global_load_lds staging ------------------
// TSTORE: write C transposed (C[col*ldc+row]) — used for weight-fusion GEMMs.
// XCD-aware chunked swizzle (T1), bijective iff nwg%8==0 (all big grids here).
template<int NT, typename TC, bool SILU, bool CUT, bool TSTORE=false>
__global__ __launch_bounds__(256) void gemm_mfma(
    const unsigned short* __restrict__ A, int lda, int K1,
    const unsigned short* __restrict__ WT, int ldw,
    TC* __restrict__ C, int ldc,
    const float* __restrict__ cutv,
    int N, int K, float scale)
{
  constexpr int NB = NT/16;
  __shared__ s8v As8[128*8];
  __shared__ s8v Bs8[NT*8];
  const int tid = threadIdx.x;
  const int wid = tid >> 6, lane = tid & 63;
  const int r15 = lane & 15, kg = lane >> 4;
  int bid = blockIdx.x + blockIdx.y * gridDim.x;
  const int nwg = gridDim.x * gridDim.y;
  if ((nwg & 7) == 0) bid = (bid & 7) * (nwg >> 3) + (bid >> 3);
  const int col0 = (bid % gridDim.x) * NT;
  const int row0 = (bid / gridDim.x) * 128;
  f4v acc[2][NB] = {};

  auto compute = [&](){
    #pragma unroll
    for (int s = 0; s < 2; s++) {
      const int cb = s*4 + kg;
      const int cx = cb ^ (r15 & 7);
      s8v a0 = As8[(wid*32      + r15)*8 + cx];
      s8v a1 = As8[(wid*32 + 16 + r15)*8 + cx];
      #pragma unroll
      for (int j = 0; j < NB; j++) {
        s8v b = Bs8[(j*16 + r15)*8 + cx];
        acc[0][j] = __builtin_amdgcn_mfma_f32_16x16x32_bf16(a0, b, acc[0][j], 0,0,0);
        acc[1][j] = __builtin_amdgcn_mfma_f32_16x16x32_bf16(a1, b, acc[1][j], 0,0,0);
      }
    }
  };

  for (int k0 = 0; k0 < K; k0 += 64) {
    #pragma unroll
    for (int i = 0; i < 4; i++) {       // A tile: 1024 segs of 16B
      int seg = i*256 + tid;
      int r = seg >> 3, ks = seg & 7;
      int ksx = ks ^ (r & 7);
      gl16(A + (size_t)(row0+r)*lda + k0 + ksx*8, &As8[i*256 + (tid & ~63)]);
    }
    #pragma unroll
    for (int i = 0; i < NT/32; i++) {   // B tile: NT*8 segs
      int seg = i*256 + tid;
      int n = seg >> 3, ks = seg & 7;
      int ksx = ks ^ (n & 7);
      gl16(WT + (size_t)(col0+n)*ldw + k0 + ksx*8, &Bs8[i*256 + (tid & ~63)]);
    }
    __syncthreads();
    compute();
    __syncthreads();
  }
  // epilogue: C/D layout col = lane&15, row = (lane>>4)*4 + j
  #pragma unroll
  for (int g=0; g<2; g++) {
    #pragma unroll
    for (int c=0; c<NB; c++) {
      int col = col0 + c*16 + r15;
      if (col >= N) continue;
      #pragma unroll
      for (int j=0;j<4;j++) {
        int row = row0 + wid*32 + g*16 + kg*4 + j;
        float v = acc[g][c][j] * scale;
        if (SILU) v = v / (1.f + __expf(-v));
        if (CUT)  v *= cutv[row];
        if (TSTORE) stC(&C[(size_t)col*ldc + row], v);
        else        stC(&C[(size_t)row*ldc + col], v);
      }
    }
  }
}

// ---------------- V init: thread per (e,m); wi = xb cols [544..672) ------------
__global__ __launch_bounds__(256) void vbuild(
    const unsigned short* __restrict__ xbc, const float* __restrict__ Y,
    unsigned short* __restrict__ V, int count)
{
  int t = blockIdx.x*256 + threadIdx.x;
  if (t >= count*32) return;
  int e = t >> 5, m = t & 31;
  const unsigned short* wr = xbc + (size_t)e*672 + 544 + m;
  float ws[4] = { b2f(wr[0]), b2f(wr[32]), b2f(wr[64]), b2f(wr[96]) };
  const float4* Y4 = (const float4*)(Y + (size_t)e*16);
  float yv[16];
  #pragma unroll
  for (int q=0;q<4;q++){ float4 f=Y4[q]; yv[q*4]=f.x; yv[q*4+1]=f.y; yv[q*4+2]=f.z; yv[q*4+3]=f.w; }
  constexpr int LOFK[16] = {0,1,1,1,2,2,2,2,2,3,3,3,3,3,3,3};
  s8v o0, o1;
  #pragma unroll
  for (int k=0;k<8;k++)  o0[k] = (short)f2b(ws[LOFK[k]]   * yv[k]);
  #pragma unroll
  for (int k=0;k<8;k++)  o1[k] = (short)f2b(ws[LOFK[8+k]] * yv[8+k]);
  s8v* vo = (s8v*)(V + (size_t)e*512 + (size_t)m*16);
  vo[0] = o0; vo[1] = o1;
}

// ---------------- CSR build: scan -> fill (histogram fused into edge_init) ----
__global__ __launch_bounds__(256) void scan_k(
    const int* __restrict__ deg, int* __restrict__ offs, int Nn)
{
  __shared__ int part[256];
  const int t = threadIdx.x;
  const int per = (Nn + 255) / 256;
  int base = t*per;
  int loc[32];
  int s = 0;
  for (int i=0;i<per;i++){ int v = (base+i<Nn)?deg[base+i]:0; loc[i]=s; s+=v; }
  part[t] = s;
  __syncthreads();
  for (int off=1; off<256; off<<=1){
    int v = (t>=off) ? part[t-off] : 0;
    __syncthreads();
    part[t] += v;
    __syncthreads();
  }
  int pre = (t==0) ? 0 : part[t-1];
  for (int i=0;i<per;i++) if (base+i<Nn) offs[base+i] = pre + loc[i];
  if (t==255) offs[Nn] = part[255];
}

__global__ __launch_bounds__(256) void fill_k(
    const int* __restrict__ rcv, int* __restrict__ cursor,
    const int* __restrict__ offs, int* __restrict__ elist, int E)
{
  int e = blockIdx.x*256 + threadIdx.x;
  if (e >= E) return;
  int r = rcv[e];
  int p = atomicAdd(&cursor[r], 1);
  elist[offs[r] + p] = e;
}

// ---------------- env build (w = bf16 cols [512..544) of xb) -------------------
__global__ __launch_bounds__(512) void env_build(
    const unsigned short* __restrict__ xb, const float* __restrict__ Y,
    const int* __restrict__ elist, const int* __restrict__ offs,
    float* __restrict__ nenv)
{
  const int n = blockIdx.x;
  const int j = threadIdx.x;          // 0..511
  const int m = j >> 4, kk = j & 15;
  const int beg = offs[n], end = offs[n+1];
  float acc = 0.f;
  for (int p = beg; p < end; ++p) {
    int e = elist[p];
    acc += b2f(xb[(size_t)e*672 + 512 + m]) * Y[(size_t)e*16 + kk];
  }
  nenv[(size_t)n*512 + j] = acc;
}

// ------------ fused tensor product + V-mix (layer 0; literal-fmac TP) ----------
// R14/R18-measured body. This round's two tp_mix-only edits:
// (1) launch_bounds (256,4): raise waves-per-EU floor (VGPR 60 <= 64, no spill
//     expected) to probe whether the metadata was capping occupancy at 42%.
// (2) pair-XOR swizzle on Ts (kp ^ ((m>>1)&7)): write conflicts 16-way -> 2-way
//     (free); mix reads stay uniform broadcasts.
__global__ __launch_bounds__(256, 4) void tp_mix(
    const float* __restrict__ nenv, const int* __restrict__ senders,
    unsigned short* __restrict__ V,
    const float* __restrict__ wm,     // layer slice: [4][32][32]
    unsigned short* __restrict__ xb, int E)
{
  __shared__ f2v Ts[8][32][8];        // pitch 16 floats; slot-XOR swizzled
  const int tid = threadIdx.x;
  const int le = tid >> 5, m = tid & 31;
  const int e = blockIdx.x*8 + le;
  const int s = senders[e];
  float env[16], v[16], acc[16];
  const float4* ne4 = (const float4*)(nenv + (size_t)s*512 + (size_t)m*16);
  #pragma unroll
  for (int q=0;q<4;q++){
    float4 f = ne4[q];
    env[q*4]=f.x; env[q*4+1]=f.y; env[q*4+2]=f.z; env[q*4+3]=f.w;
  }
  const s8v* vv = (const s8v*)(V + (size_t)e*512 + (size_t)m*16);
  s8v v0 = vv[0], v1 = vv[1];
  #pragma unroll
  for (int q=0;q<8;q++){ v[q] = b2f((unsigned short)v0[q]); v[8+q] = b2f((unsigned short)v1[q]); }
  #pragma unroll
  for (int k=0;k<16;k++) acc[k] = 0.f;

  tp_pair<0,0>(env,v,acc); tp_pair<0,1>(env,v,acc); tp_pair<0,2>(env,v,acc); tp_pair<0,3>(env,v,acc);
  tp_pair<1,0>(env,v,acc); tp_pair<1,1>(env,v,acc); tp_pair<1,2>(env,v,acc); tp_pair<1,3>(env,v,acc);
  tp_pair<2,0>(env,v,acc); tp_pair<2,1>(env,v,acc); tp_pair<2,2>(env,v,acc); tp_pair<2,3>(env,v,acc);
  tp_pair<3,0>(env,v,acc); tp_pair<3,1>(env,v,acc); tp_pair<3,2>(env,v,acc); tp_pair<3,3>(env,v,acc);

  xb[(size_t)e*672 + 512 + m] = f2b(acc[0]);   // t0 (TN3 folded into W3V)

  const int msw = (m >> 1) & 7;       // write swizzle key (2-way banks, free)
  #pragma unroll
  for (int kp=0;kp<8;kp++){
    f2v t2; t2[0] = acc[2*kp]; t2[1] = acc[2*kp+1];
    Ts[le][m][kp ^ msw] = t2;
  }
  // (no barrier: same-wave producer/consumer)
  f2v o2[8];
  #pragma unroll
  for (int kp=0;kp<8;kp++){ o2[kp][0]=0.f; o2[kp][1]=0.f; }
  #pragma unroll
  for (int mm=0; mm<32; mm++) {
    const int rsw = (mm >> 1) & 7;    // read back with same slot-XOR (broadcast)
    float w0 = wm[        mm*32 + m];
    float w1 = wm[1024 +  mm*32 + m];
    float w2 = wm[2048 +  mm*32 + m];
    float w3 = wm[3072 +  mm*32 + m];
    const f2v* tr = Ts[le][mm];
    f2v p01; p01[0]=w0; p01[1]=w1;
    f2v p11; p11[0]=w1; p11[1]=w1;
    f2v p22; p22[0]=w2; p22[1]=w2;
    f2v p23; p23[0]=w2; p23[1]=w3;
    f2v p33; p33[0]=w3; p33[1]=w3;
    o2[0] += tr[0 ^ rsw]*p01; o2[1] += tr[1 ^ rsw]*p11; o2[2] += tr[2 ^ rsw]*p22; o2[3] += tr[3 ^ rsw]*p22;
    o2[4] += tr[4 ^ rsw]*p23; o2[5] += tr[5 ^ rsw]*p33; o2[6] += tr[6 ^ rsw]*p33; o2[7] += tr[7 ^ rsw]*p33;
  }
  s8v oa, ob;
  #pragma unroll
  for (int kp=0;kp<4;kp++){
    oa[2*kp]   = (short)f2b(o2[kp][0]   * 0.17677669529663689f); // 1/sqrt(32)
    oa[2*kp+1] = (short)f2b(o2[kp][1]   * 0.17677669529663689f);
    ob[2*kp]   = (short)f2b(o2[4+kp][0] * 0.17677669529663689f);
    ob[2*kp+1] = (short)f2b(o2[4+kp][1] * 0.17677669529663689f);
  }
  s8v* vo = (s8v*)(V + (size_t)e*512 + (size_t)m*16);
  vo[0] = oa; vo[1] = ob;
}

// ------------ last-layer TP: only l3=0 survives; t0 -> xb bf16 ------------------
__global__ __launch_bounds__(256) void tp_last(
    const float* __restrict__ nenv, const int* __restrict__ senders,
    const unsigned short* __restrict__ V, unsigned short* __restrict__ xb, int E)
{
  int t = blockIdx.x*256 + threadIdx.x;
  int e = t >> 5, m = t & 31;
  if (e >= E) return;
  int s = senders[e];
  float env[16], v[16], acc[16];
  const float4* ne4 = (const float4*)(nenv + (size_t)s*512 + (size_t)m*16);
  #pragma unroll
  for (int q=0;q<4;q++){
    float4 f = ne4[q];
    env[q*4]=f.x; env[q*4+1]=f.y; env[q*4+2]=f.z; env[q*4+3]=f.w;
  }
  const s8v* vv = (const s8v*)(V + (size_t)e*512 + (size_t)m*16);
  s8v v0 = vv[0], v1 = vv[1];
  #pragma unroll
  for (int q=0;q<8;q++){ v[q] = b2f((unsigned short)v0[q]); v[8+q] = b2f((unsigned short)v1[q]); }
  #pragma unroll
  for (int k=0;k<16;k++) acc[k] = 0.f;
  tp_tri<0,0,0>(env,v,acc); tp_tri<1,1,0>(env,v,acc);
  tp_tri<2,2,0>(env,v,acc); tp_tri<3,3,0>(env,v,acc);
  xb[(size_t)e*672 + 512 + m] = f2b(acc[0]);
}

// -------- fused final output: out[e] = rs512^2 * cut[e] * dot(h[e], fv) --------
__global__ __launch_bounds__(256) void out_fused(
    const unsigned short* __restrict__ h, const float* __restrict__ fv,
    const float* __restrict__ cutv, float* __restrict__ out, int count)
{
  int gw = (blockIdx.x*256 + threadIdx.x) >> 6;
  int lane = threadIdx.x & 63;
  if (gw >= count) return;
  const s8v* xr = (const s8v*)(h + (size_t)gw*512);
  s8v chunk = xr[lane];
  float s = 0.f;
  #pragma unroll
  for (int j=0;j<8;j++) s += b2f((unsigned short)chunk[j]) * fv[lane*8 + j];
  #pragma unroll
  for (int off=32; off; off>>=1) s += __shfl_down(s, off);
  if (lane == 0)
    out[gw] = s * cutv[gw] * (0.044194173824159216f * 0.044194173824159216f);
}

// ---------------- workspace sizing ----------------
static inline size_t alup(size_t b){ return (b + 255) & ~(size_t)255; }
static size_t need_bytes(int E, int N, int chd){
  size_t s = 0;
  s += alup((size_t)E*16*4);            // Yb
  s += alup((size_t)E*4);               // cutb
  s += alup((size_t)N*512*4);           // nenv
  s += alup((size_t)E*64*2);            // feat
  s += alup((size_t)chd*512*2);         // cbuf
  s += alup((size_t)E*512*2);           // Vb
  s += alup((size_t)E*672*2);           // xb (x | w/t0 | wi)
  s += alup((size_t)512*64*2);          // we0T
  s += alup((size_t)768*512*2);         // weF (we1T + fused wenv0 + fused winit)
  s += alup((size_t)128*512*2);         // winT
  s += alup((size_t)2*32*512*2);        // wenvT
  s += alup((size_t)2*512*576*2);       // wl0T (Kpad 576)
  s += alup((size_t)640*512*2);         // wl1F (wlat1T_l0 + fused wenv1)
  s += alup((size_t)512*512*2);         // we1c
  s += alup((size_t)512*512*2);         // wl1c
  s += alup(512*4);                     // fv
  s += alup((size_t)N*4);               // deg
  s += alup(((size_t)N+1)*4);           // offs
  s += alup((size_t)N*4);               // cursor
  s += alup((size_t)E*4);               // elist
  return s;
}

// ---------------- launch ----------------
extern "C" void kernel_launch(void* const* d_in, const int* in_sizes, int n_in,
                              void* d_out, int out_size, void* d_ws, size_t ws_size,
                              hipStream_t stream)
{
  const float* node_attrs = (const float*)d_in[0];
  const float* vectors    = (const float*)d_in[1];
  const float* we0        = (const float*)d_in[2];
  const float* we1        = (const float*)d_in[3];
  const float* winit      = (const float*)d_in[4];
  const float* wenv       = (const float*)d_in[5];
  const float* wlat0      = (const float*)d_in[6];
  const float* wlat1      = (const float*)d_in[7];
  const float* wmix       = (const float*)d_in[8];
  const float* wout       = (const float*)d_in[9];
  const int*   senders    = (const int*)d_in[10];
  const int*   receivers  = (const int*)d_in[11];
  float* out = (float*)d_out;
  const int E = in_sizes[1] / 3;
  const int N = in_sizes[0] / 16;

  int CHD = -1;
  const int tiers[4] = {E, E/2, E/4, CH};
  for (int i=0;i<4;i++){
    if (tiers[i] >= CH && need_bytes(E, N, tiers[i]) <= ws_size){ CHD = tiers[i]; break; }
  }
  if (CHD < 0) return;                  // diagnostic clean fail

  char* base = (char*)d_ws;
  size_t off = 0;
  auto carve = [&](size_t b) -> char* { char* p = base + off; off += alup(b); return p; };
  float*          Yb    = (float*)carve((size_t)E*16*4);
  float*          cutb  = (float*)carve((size_t)E*4);
  float*          nenv  = (float*)carve((size_t)N*512*4);
  unsigned short* feat  = (unsigned short*)carve((size_t)E*64*2);
  unsigned short* cbuf  = (unsigned short*)carve((size_t)CHD*512*2);
  unsigned short* Vb    = (unsigned short*)carve((size_t)E*512*2);
  unsigned short* xb    = (unsigned short*)carve((size_t)E*672*2);
  unsigned short* we0T  = (unsigned short*)carve((size_t)512*64*2);
  unsigned short* weF   = (unsigned short*)carve((size_t)768*512*2);
  unsigned short* winT  = (unsigned short*)carve((size_t)128*512*2);
  unsigned short* wenvT = (unsigned short*)carve((size_t)2*32*512*2);
  unsigned short* wl0T  = (unsigned short*)carve((size_t)2*512*576*2);
  unsigned short* wl1F  = (unsigned short*)carve((size_t)640*512*2);
  unsigned short* we1c  = (unsigned short*)carve((size_t)512*512*2);
  unsigned short* wl1c  = (unsigned short*)carve((size_t)512*512*2);
  float*          fv    = (float*)carve(512*4);
  int*            deg   = (int*)carve((size_t)N*4);
  int*            offs  = (int*)carve(((size_t)N+1)*4);
  int*            cursor= (int*)carve((size_t)N*4);
  int*            elist = (int*)carve((size_t)E*4);

  const float rs40  = 0.15811388300841897f;  // 1/sqrt(40)
  const float rs512 = 0.044194173824159216f; // 1/sqrt(512)
  const float rs544 = 0.042874646285627205f; // 1/sqrt(544)

  dim3 blk(256);
  // zero CSR scratch first (edge_init's fused histogram needs deg=0)
  hipMemsetAsync(deg, 0, (size_t)N*4, stream);
  hipMemsetAsync(cursor, 0, (size_t)N*4, stream);

  // batched weight conversion (one dispatch, 10 segments)
  WDesc wd;
  auto seg = [&](int i, const float* W, unsigned short* WT, int K, int Nn, int Kpad, int trans){
    int elems = trans ? Nn*Kpad : K*Nn;
    wd.s[i] = { W, WT, K, Nn, Kpad, (elems + 255)/256, trans };
  };
  seg(0, we0,   we0T, 40, 512, 64, 1);
  seg(1, we1,   weF,  512, 512, 512, 1);                                  // rows 0..512
  seg(2, winit, winT, 512, 128, 512, 1);
  seg(3, wenv,                  wenvT,                  512, 32, 512, 1);
  seg(4, wenv + (size_t)512*32, wenvT + (size_t)32*512, 512, 32, 512, 1);
  seg(5, wlat0,                   wl0T,                   544, 512, 576, 1);
  seg(6, wlat0 + (size_t)544*512, wl0T + (size_t)512*576, 544, 512, 576, 1);
  seg(7, wlat1,                   wl1F,  512, 512, 512, 1);               // rows 0..512
  seg(8, we1,   we1c, 512, 512, 512, 0);                                  // straight copy
  seg(9, wlat1, wl1c, 512, 512, 512, 0);
  int totblk = 0;
  for (int i=0;i<10;i++) totblk += wd.s[i].nblk;
  wconv_all<<<totblk, blk, 0, stream>>>(wd);
  wfuse_vec<<<2, blk, 0, stream>>>(wlat1 + (size_t)512*512, wout, fv);

  // weight-fusion GEMMs (write transposed, bf16):
  gemm_mfma<64,unsigned short,false,false,true><<<dim3(1,4), blk, 0, stream>>>(
      we1c, 512, 512, wenvT, 512, weF + (size_t)512*512, 512, nullptr, 32, 512, rs512*0.25f);
  gemm_mfma<128,unsigned short,false,false,true><<<dim3(1,4), blk, 0, stream>>>(
      we1c, 512, 512, winT, 512, weF + (size_t)544*512, 512, nullptr, 128, 512, rs512);
  gemm_mfma<64,unsigned short,false,false,true><<<dim3(1,4), blk, 0, stream>>>(
      wl1c, 512, 512, wenvT + (size_t)32*512, 512, wl1F + (size_t)512*512, 512, nullptr, 32, 512, rs512*0.25f);

  edge_init<<<E/256, blk, 0, stream>>>(vectors, node_attrs, senders, receivers, feat, Yb, cutb, deg, E);

  // CSR of receivers (histogram fused into edge_init)
  scan_k<<<1, blk, 0, stream>>>(deg, offs, N);
  fill_k<<<(E+255)/256, blk, 0, stream>>>(receivers, cursor, offs, elist, E);

  // edge embedding: feat -> h (silu) -> [x | w0 | wi] (cut) ; V init
  for (int c0 = 0; c0 < E; c0 += CHD) {
    gemm_mfma<128,unsigned short,true,false><<<dim3(4, CHD/128), blk, 0, stream>>>(
        feat + (size_t)c0*64, 64, 64, we0T, 64, cbuf, 512, nullptr, 512, 64, rs40);
    gemm_mfma<128,unsigned short,false,true><<<dim3(6, CHD/128), blk, 0, stream>>>(
        cbuf, 512, 512, weF, 512, xb + (size_t)c0*672, 672, cutb + c0, 672, 512, rs512);
    vbuild<<<(CHD*32)/256, blk, 0, stream>>>(xb + (size_t)c0*672, Yb + (size_t)c0*16, Vb + (size_t)c0*512, CHD);
  }

  for (int layer = 0; layer < 2; ++layer) {
    env_build<<<N, 512, 0, stream>>>(xb, Yb, elist, offs, nenv);
    if (layer == 0)
      tp_mix<<<E/8, blk, 0, stream>>>(nenv, senders, Vb,
          wmix, xb, E);
    else
      tp_last<<<(E*32)/256, blk, 0, stream>>>(nenv, senders, Vb, xb, E);
    for (int c0 = 0; c0 < E; c0 += CHD) {
      // lat0: pure K=576 GEMM over [x | t0 | (dead wi, zero-weighted)]
      gemm_mfma<128,unsigned short,true,false><<<dim3(4, CHD/128), blk, 0, stream>>>(
          xb + (size_t)c0*672, 672, 576, wl0T + (size_t)layer*512*576, 576,
          cbuf, 512, nullptr, 512, 576, rs544);
      if (layer == 0)
        // lat1 + fused wenv of next layer
        gemm_mfma<128,unsigned short,false,true><<<dim3(5, CHD/128), blk, 0, stream>>>(
            cbuf, 512, 512, wl1F, 512, xb + (size_t)c0*672, 672, cutb + c0, 544, 512, rs512);
      else
        // final lat1 GEMM eliminated: out = rs512^2 * cut * <h, wlat1@wout>
        out_fused<<<CHD/4, blk, 0, stream>>>(cbuf, fv, cutb + c0, out + c0, CHD);
    }
  }
}